// Round 1
// baseline (420.607 us; speedup 1.0000x reference)
//
#include <hip/hip_runtime.h>
#include <hip/hip_fp16.h>
#include <math.h>

// ---------------------------------------------------------------------------
// GAT encoder, 2 layers.
//   GEMMs: 2-term split-bf16 MFMA (A_hi(rne)*B_hi + A_hi*B_lo). B pre-split
//          once into transposed bf16 hi/lo tables (zero conversion VALU in
//          the GEMM staging loop). Epilogue writes h fp16 + per-head a_s
//          (fp16) / a_d (fp32).
//   fill_rec computes the softmax weight w = exp(leaky(a_s[src]+a_d[dst]))
//          per edge per head (a_d reads are CSR-sequential) and stores
//          rec[i] = {src, w0|w1, w2|w3, 0} (fp16 weights).
//   Aggregation: 1 node/wave (64 lanes x 8B = one coalesced 512B row gather
//          per edge), wave-uniform loop control, depth-4 rotation-free
//          software pipeline. Inner loop: decode w, l+=w, 4 fma.
// ---------------------------------------------------------------------------

#define LEAKY_SLOPE 0.2f

typedef __attribute__((ext_vector_type(8))) short short8v;   // 8 bf16
typedef __attribute__((ext_vector_type(4))) float float4v;

// ---------------- CSR build ----------------

__global__ void hist_kernel(const int* __restrict__ ei, int* __restrict__ cnt,
                            int E, int Etot) {
    int e = blockIdx.x * blockDim.x + threadIdx.x;
    if (e >= Etot) return;
    int dst = (e < E) ? ei[E + e] : (e - E);
    atomicAdd(&cnt[dst], 1);
}

__global__ __launch_bounds__(1024) void scan_block(const int* __restrict__ cnt,
                                                   int* __restrict__ row_start,
                                                   int* __restrict__ partials,
                                                   int n) {
    __shared__ int wsum[16];
    int tid = threadIdx.x, lane = tid & 63, wid = tid >> 6;
    int gi = blockIdx.x * 1024 + tid;
    int v = (gi < n) ? cnt[gi] : 0;
    int x = v;
#pragma unroll
    for (int off = 1; off < 64; off <<= 1) {
        int y = __shfl_up(x, off, 64);
        if (lane >= off) x += y;
    }
    if (lane == 63) wsum[wid] = x;
    __syncthreads();
    if (wid == 0 && lane < 16) {
        int w = wsum[lane];
#pragma unroll
        for (int off = 1; off < 16; off <<= 1) {
            int y = __shfl_up(w, off, 16);
            if (lane >= off) w += y;
        }
        wsum[lane] = w;
    }
    __syncthreads();
    int excl = x - v + ((wid > 0) ? wsum[wid - 1] : 0);
    if (gi < n) row_start[gi] = excl;
    if (tid == 1023) partials[blockIdx.x] = wsum[15];
}

__global__ void scan_partials(int* __restrict__ partials, int nb) {
    int lane = threadIdx.x;  // 64 threads, nb <= 64
    int v = (lane < nb) ? partials[lane] : 0;
    int x = v;
#pragma unroll
    for (int off = 1; off < 64; off <<= 1) {
        int y = __shfl_up(x, off, 64);
        if (lane >= off) x += y;
    }
    if (lane < nb) partials[lane] = x - v;
    if (lane == nb - 1) partials[nb] = x;
}

__global__ __launch_bounds__(1024) void scan_add(int* __restrict__ row_start,
                                                 const int* __restrict__ partials,
                                                 int n, int nb) {
    int gi = blockIdx.x * 1024 + threadIdx.x;
    if (gi < n) row_start[gi] += partials[blockIdx.x];
    if (gi == 0) row_start[n] = partials[nb];
}

__global__ void scatter_kernel(const int* __restrict__ ei,
                               const int* __restrict__ row_start,
                               int* __restrict__ fill,
                               int2* __restrict__ edge_sd, int E, int Etot) {
    int e = blockIdx.x * blockDim.x + threadIdx.x;
    if (e >= Etot) return;
    int src, dst;
    if (e < E) { src = ei[e]; dst = ei[E + e]; }
    else       { src = e - E; dst = e - E; }
    int pos = row_start[dst] + atomicAdd(&fill[dst], 1);
    edge_sd[pos] = make_int2(src, dst);
}

// per-layer: rec[i] = {src, w0|w1, w2|w3, pad}, w = exp(leaky(a_s+a_d)) fp16
__global__ void fill_rec(const int2* __restrict__ edge_sd,
                         const __half* __restrict__ a_s_h,
                         const float* __restrict__ a_d,
                         uint4* __restrict__ rec, int Etot) {
    int i = blockIdx.x * blockDim.x + threadIdx.x;
    if (i >= Etot) return;
    int2 sd = edge_sd[i];
    uint2 as2 = *(const uint2*)&a_s_h[(size_t)sd.x * 4];
    float4 ad4 = *(const float4*)&a_d[(size_t)sd.y * 4];
    float2 f01 = __half22float2(*(const __half2*)&as2.x);
    float2 f23 = __half22float2(*(const __half2*)&as2.y);
    float e0 = f01.x + ad4.x, e1 = f01.y + ad4.y;
    float e2 = f23.x + ad4.z, e3 = f23.y + ad4.w;
    e0 = (e0 > 0.f) ? e0 : LEAKY_SLOPE * e0;
    e1 = (e1 > 0.f) ? e1 : LEAKY_SLOPE * e1;
    e2 = (e2 > 0.f) ? e2 : LEAKY_SLOPE * e2;
    e3 = (e3 > 0.f) ? e3 : LEAKY_SLOPE * e3;
    __half2 w01 = __floats2half2_rn(__expf(e0), __expf(e1));
    __half2 w23 = __floats2half2_rn(__expf(e2), __expf(e3));
    uint4 r = {(unsigned)sd.x, *(unsigned*)&w01, *(unsigned*)&w23, 0u};
    rec[i] = r;
}

// ---------------- split-bf16 helpers ----------------

__device__ __forceinline__ short bf16_rne(float f) {
    unsigned u = __float_as_uint(f);
    return (short)((u + 0x7FFFu + ((u >> 16) & 1u)) >> 16);
}

__device__ __forceinline__ void split_bf16(float f, short& hi, short& lo) {
    unsigned u = __float_as_uint(f);
    hi = (short)(u >> 16);
    float fhi = __uint_as_float(u & 0xFFFF0000u);
    float flo = f - fhi;  // exact
    lo = (short)(__float_as_uint(flo) >> 16);
}

// B [K][256] fp32 -> Bt_hi/Bt_lo [256][K] bf16 (transposed, split once)
__global__ void split_B(const float* __restrict__ B, short* __restrict__ Bt_hi,
                        short* __restrict__ Bt_lo, int K) {
    int idx = blockIdx.x * 256 + threadIdx.x;
    if (idx >= K * 256) return;
    int k = idx >> 8, c = idx & 255;
    short hi, lo;
    split_bf16(B[idx], hi, lo);
    Bt_hi[c * K + k] = hi;
    Bt_lo[c * K + k] = lo;
}

// ---------------- split-bf16 MFMA GEMM + fused attention dots ---------------
// C[M,256] = A[M,K] @ B[K,256], C stored fp16. A fp32 (rne) or bf16.
// 2-term: A_hi(rne) * (B_hi + B_lo). 128x128 tile, BK=32, 2x2 waves.

template <int K, bool ABF16>
__global__ __launch_bounds__(256) void gemm_mfma(
    const void* __restrict__ Ap, const short* __restrict__ Bt_hi,
    const short* __restrict__ Bt_lo, __half* __restrict__ Ch,
    const float* __restrict__ att_src, const float* __restrict__ att_dst,
    __half* __restrict__ a_s_out, float* __restrict__ a_d_out, int M) {
    __shared__ short As_hi[128][40];   // [m][k], pad 32->40
    __shared__ short Bs_hi[128][40];   // [n][k] (transposed)
    __shared__ short Bs_lo[128][40];

    const int col0 = (blockIdx.x & 1) * 128;
    const int row0 = (blockIdx.x >> 1) * 128;
    const int tid = threadIdx.x;
    const int lane = tid & 63;
    const int wave = tid >> 6;
    const int wr = wave >> 1, wc = wave & 1;
    const int quad = lane >> 4, lc = lane & 15;

    float4v acc[4][4] = {};

    for (int k0 = 0; k0 < K; k0 += 32) {
        if constexpr (ABF16) {
            const short* Abf = (const short*)Ap;
#pragma unroll
            for (int i = 0; i < 2; i++) {
                int slot = tid + i * 256;       // 0..511
                int r = slot >> 2;              // 0..127
                int ko = (slot & 3) * 8;        // 0,8,16,24
                short8v v = {};
                int gr = row0 + r;
                if (gr < M) v = *(const short8v*)&Abf[(size_t)gr * K + k0 + ko];
                *(short8v*)&As_hi[r][ko] = v;
            }
        } else {
            const float* A = (const float*)Ap;
#pragma unroll
            for (int i = 0; i < 4; i++) {
                int slot = tid + i * 256;
                int r = slot >> 3;
                int kq = (slot & 7) * 4;
                float4 v = {0.f, 0.f, 0.f, 0.f};
                int gr = row0 + r;
                if (gr < M) v = *(const float4*)&A[(size_t)gr * K + k0 + kq];
                short4 h4;
                h4.x = bf16_rne(v.x); h4.y = bf16_rne(v.y);
                h4.z = bf16_rne(v.z); h4.w = bf16_rne(v.w);
                *(short4*)&As_hi[r][kq] = h4;
            }
        }
        // B staging: pure 16B vector loads from pre-split transposed tables
#pragma unroll
        for (int i = 0; i < 2; i++) {
            int slot = tid + i * 256;
            int r = slot >> 2;                  // col within tile 0..127
            int ko = (slot & 3) * 8;
            size_t gb = (size_t)(col0 + r) * K + k0 + ko;
            short8v vh = *(const short8v*)&Bt_hi[gb];
            short8v vl = *(const short8v*)&Bt_lo[gb];
            *(short8v*)&Bs_hi[r][ko] = vh;
            *(short8v*)&Bs_lo[r][ko] = vl;
        }
        __syncthreads();

        short8v a_hi[4], b_hi[4], b_lo[4];
#pragma unroll
        for (int mt = 0; mt < 4; mt++) {
            int r = wr * 64 + mt * 16 + lc;
            a_hi[mt] = *(const short8v*)&As_hi[r][quad * 8];
        }
#pragma unroll
        for (int nt = 0; nt < 4; nt++) {
            int n = wc * 64 + nt * 16 + lc;
            b_hi[nt] = *(const short8v*)&Bs_hi[n][quad * 8];
            b_lo[nt] = *(const short8v*)&Bs_lo[n][quad * 8];
        }
#pragma unroll
        for (int mt = 0; mt < 4; mt++)
#pragma unroll
            for (int nt = 0; nt < 4; nt++) {
                acc[mt][nt] = __builtin_amdgcn_mfma_f32_16x16x32_bf16(
                    a_hi[mt], b_hi[nt], acc[mt][nt], 0, 0, 0);
                acc[mt][nt] = __builtin_amdgcn_mfma_f32_16x16x32_bf16(
                    a_hi[mt], b_lo[nt], acc[mt][nt], 0, 0, 0);
            }
        __syncthreads();
    }

    // ---- epilogue: wave's 64 cols = head; C/D: col=lc(+nt*16), row=quad*4+r
    const int head = (col0 >> 6) + wc;
    float as_c[4], ad_c[4];
#pragma unroll
    for (int nt = 0; nt < 4; nt++) {
        as_c[nt] = att_src[head * 64 + nt * 16 + lc];
        ad_c[nt] = att_dst[head * 64 + nt * 16 + lc];
    }

#pragma unroll
    for (int mt = 0; mt < 4; mt++) {
#pragma unroll
        for (int r = 0; r < 4; r++) {
            int gr = row0 + wr * 64 + mt * 16 + quad * 4 + r;
            float ps = 0.f, pd = 0.f;
#pragma unroll
            for (int nt = 0; nt < 4; nt++) {
                float c = acc[mt][nt][r];
                ps = fmaf(c, as_c[nt], ps);
                pd = fmaf(c, ad_c[nt], pd);
                if (gr < M)
                    Ch[(size_t)gr * 256 + col0 + wc * 64 + nt * 16 + lc] =
                        __float2half(c);
            }
#pragma unroll
            for (int off = 1; off < 16; off <<= 1) {
                ps += __shfl_xor(ps, off, 64);
                pd += __shfl_xor(pd, off, 64);
            }
            if (lc == 0 && gr < M) {
                a_s_out[gr * 4 + head] = __float2half(ps);
                a_d_out[gr * 4 + head] = pd;
            }
        }
    }
}

// ---------------- fused aggregate + bias + elu ----------------
// 1 node/wave: 64 lanes x 8B = one coalesced 512B h-row gather per edge.
// Wave-uniform loop control, depth-4 rotation-free pipeline.
// Inner loop per edge: decode precomputed fp16 w, l += w, 4 fma.

template <bool OUT_BF16>
__global__ __launch_bounds__(256) void gat_aggregate(
    const __half* __restrict__ hh, const uint4* __restrict__ rec,
    const int* __restrict__ row_start, const float* __restrict__ bias,
    void* __restrict__ outp, int n) {
    int node = (blockIdx.x * blockDim.x + threadIdx.x) >> 6;
    if (node >= n) return;                 // wave-uniform
    int lane = threadIdx.x & 63;
    int head = lane >> 4;                  // 4 channels/lane: lane*4..+3

    int beg = row_start[node];
    int end = row_start[node + 1];
    int em1 = end - 1;                     // degree >= 1 (self-loops)

    float l = 0.f;
    float acc[4] = {};

    uint4 r0 = rec[beg];
    uint4 r1 = rec[min(beg + 1, em1)];
    uint4 r2 = rec[min(beg + 2, em1)];
    uint4 r3 = rec[min(beg + 3, em1)];

#define GATH(rr) (*(const uint2*)&hh[(size_t)(rr).x * 256 + lane * 4])
#define PROC(rr, vv)                                                      \
    {                                                                     \
        unsigned u = (head & 2) ? (rr).z : (rr).y;                        \
        unsigned short us = (head & 1) ? (unsigned short)(u >> 16)        \
                                       : (unsigned short)(u & 0xFFFFu);   \
        float w = __half2float(*(const __half*)&us);                      \
        l += w;                                                           \
        const __half2* hp = (const __half2*)&(vv);                        \
        float2 f0 = __half22float2(hp[0]);                                \
        float2 f1 = __half22float2(hp[1]);                                \
        acc[0] = fmaf(w, f0.x, acc[0]);                                   \
        acc[1] = fmaf(w, f0.y, acc[1]);                                   \
        acc[2] = fmaf(w, f1.x, acc[2]);                                   \
        acc[3] = fmaf(w, f1.y, acc[3]);                                   \
    }

    uint2 h0 = GATH(r0);
    uint2 h1 = GATH(r1);
    uint2 h2 = GATH(r2);
    uint2 h3;

    int s = beg;
    while (s < end) {
        // k = 0 : slot s
        h3 = GATH(r3);
        PROC(r0, h0);
        r0 = rec[min(s + 4, em1)];
        if (++s >= end) break;
        // k = 1
        h0 = GATH(r0);
        PROC(r1, h1);
        r1 = rec[min(s + 4, em1)];
        if (++s >= end) break;
        // k = 2
        h1 = GATH(r1);
        PROC(r2, h2);
        r2 = rec[min(s + 4, em1)];
        if (++s >= end) break;
        // k = 3
        h2 = GATH(r2);
        PROC(r3, h3);
        r3 = rec[min(s + 4, em1)];
        ++s;
    }
#undef GATH
#undef PROC

    float rcp = 1.f / l;
    float4 b = *(const float4*)&bias[lane * 4];
    float o[4];
    o[0] = fmaf(acc[0], rcp, b.x);
    o[1] = fmaf(acc[1], rcp, b.y);
    o[2] = fmaf(acc[2], rcp, b.z);
    o[3] = fmaf(acc[3], rcp, b.w);
#pragma unroll
    for (int j = 0; j < 4; j++)
        o[j] = (o[j] > 0.f) ? o[j] : __expf(o[j]) - 1.f;
    if constexpr (OUT_BF16) {
        short ob[4];
#pragma unroll
        for (int j = 0; j < 4; j++) ob[j] = bf16_rne(o[j]);
        short* outb = (short*)outp;
        *(short4*)&outb[(size_t)node * 256 + lane * 4] = *(short4*)&ob[0];
    } else {
        float* outf = (float*)outp;
        *(float4*)&outf[(size_t)node * 256 + lane * 4] = *(float4*)&o[0];
    }
}

// ---------------- launch ----------------

extern "C" void kernel_launch(void* const* d_in, const int* in_sizes, int n_in,
                              void* d_out, int out_size, void* d_ws, size_t ws_size,
                              hipStream_t stream) {
    const float* x   = (const float*)d_in[0];
    const int*   ei  = (const int*)d_in[1];
    const float* W1  = (const float*)d_in[2];
    const float* as1 = (const float*)d_in[3];
    const float* ad1 = (const float*)d_in[4];
    const float* b1  = (const float*)d_in[5];
    const float* W2  = (const float*)d_in[6];
    const float* as2 = (const float*)d_in[7];
    const float* ad2 = (const float*)d_in[8];
    const float* b2  = (const float*)d_in[9];
    float* out = (float*)d_out;

    const int N = in_sizes[0] / 128;
    const int E = in_sizes[1] / 2;
    const int Etot = E + N;
    const int NB = (N + 1023) / 1024;   // scan blocks (<= 64)

    // workspace layout (16B-aligned segments first)
    __half* h_half = (__half*)d_ws;                        // N*256 fp16
    short*  x1_bf  = (short*)(h_half + (size_t)N * 256);   // N*256 bf16
    uint4*  rec    = (uint4*)(x1_bf + (size_t)N * 256);    // Etot x 16B
    __half* a_s_h  = (__half*)(rec + Etot);                // N*4 fp16
    float*  a_d    = (float*)(a_s_h + (size_t)N * 4);      // N*4 fp32
    short*  Bt1h   = (short*)(a_d + (size_t)N * 4);        // 256*128 bf16
    short*  Bt1l   = Bt1h + 256 * 128;
    short*  Bt2h   = Bt1l + 256 * 128;                     // 256*256 bf16
    short*  Bt2l   = Bt2h + 256 * 256;
    int*    cnt    = (int*)(Bt2l + 256 * 256);             // N
    int*    fill   = cnt + N;                              // N
    int*    row_st = fill + N;                             // N+2 (pad for align)
    int2*   edge_sd = (int2*)(row_st + (N + 2));           // Etot x 8B
    int*    partials = (int*)(edge_sd + Etot);             // NB+1

    // pre-split both weight matrices (independent of everything else)
    split_B<<<128, 256, 0, stream>>>(W1, Bt1h, Bt1l, 128);
    split_B<<<256, 256, 0, stream>>>(W2, Bt2h, Bt2l, 256);

    hipMemsetAsync(cnt, 0, sizeof(int) * 2 * (size_t)N, stream);  // cnt + fill
    int eblocks = (Etot + 255) / 256;
    hist_kernel<<<eblocks, 256, 0, stream>>>(ei, cnt, E, Etot);
    scan_block<<<NB, 1024, 0, stream>>>(cnt, row_st, partials, N);
    scan_partials<<<1, 64, 0, stream>>>(partials, NB);
    scan_add<<<NB, 1024, 0, stream>>>(row_st, partials, N, NB);
    scatter_kernel<<<eblocks, 256, 0, stream>>>(ei, row_st, fill, edge_sd, E, Etot);

    dim3 ggrid(2 * ((N + 127) / 128));
    int ablocks = (N + 3) / 4;   // 4 nodes (waves) per 256-thread block

    // layer 1
    gemm_mfma<128, false><<<ggrid, 256, 0, stream>>>(x, Bt1h, Bt1l, h_half,
                                                     as1, ad1, a_s_h, a_d, N);
    fill_rec<<<eblocks, 256, 0, stream>>>(edge_sd, a_s_h, a_d, rec, Etot);
    gat_aggregate<true><<<ablocks, 256, 0, stream>>>(h_half, rec, row_st,
                                                     b1, x1_bf, N);
    // layer 2
    gemm_mfma<256, true><<<ggrid, 256, 0, stream>>>(x1_bf, Bt2h, Bt2l, h_half,
                                                    as2, ad2, a_s_h, a_d, N);
    fill_rec<<<eblocks, 256, 0, stream>>>(edge_sd, a_s_h, a_d, rec, Etot);
    gat_aggregate<false><<<ablocks, 256, 0, stream>>>(h_half, rec, row_st,
                                                      b2, out, N);
}

// Round 2
// 402.075 us; speedup vs baseline: 1.0461x; 1.0461x over previous
//
#include <hip/hip_runtime.h>
#include <hip/hip_fp16.h>
#include <math.h>

// ---------------------------------------------------------------------------
// GAT encoder, 2 layers.
//   GEMMs: 2-term split-bf16 MFMA (A_hi(rne)*B_hi + A_hi*B_lo). B pre-split
//          once into transposed bf16 hi/lo tables. Epilogue writes h fp16 +
//          per-head a_s (fp16) / a_d (fp32).
//   fill_rec computes softmax weight w = exp(leaky(a_s[src]+a_d[dst])) per
//          edge per head; rec[i] = {src, w0|w1, w2|w3, 0} (fp16 weights).
//   Aggregation: 1 node/wave, 2 EDGES of that node per iteration
//          (lanes 0-31 = edge p, lanes 32-63 = edge p+1; 16B/lane -> one
//          1KB gather instruction per pair). Wave-uniform loop control,
//          depth-3 rotation-free software pipeline; cross-half shfl reduce.
//          Inner loop per pair: decode 2 w, 16 fma.
// ---------------------------------------------------------------------------

#define LEAKY_SLOPE 0.2f

typedef __attribute__((ext_vector_type(8))) short short8v;   // 8 bf16
typedef __attribute__((ext_vector_type(4))) float float4v;

// ---------------- CSR build ----------------

__global__ void hist_kernel(const int* __restrict__ ei, int* __restrict__ cnt,
                            int E, int Etot) {
    int e = blockIdx.x * blockDim.x + threadIdx.x;
    if (e >= Etot) return;
    int dst = (e < E) ? ei[E + e] : (e - E);
    atomicAdd(&cnt[dst], 1);
}

__global__ __launch_bounds__(1024) void scan_block(const int* __restrict__ cnt,
                                                   int* __restrict__ row_start,
                                                   int* __restrict__ partials,
                                                   int n) {
    __shared__ int wsum[16];
    int tid = threadIdx.x, lane = tid & 63, wid = tid >> 6;
    int gi = blockIdx.x * 1024 + tid;
    int v = (gi < n) ? cnt[gi] : 0;
    int x = v;
#pragma unroll
    for (int off = 1; off < 64; off <<= 1) {
        int y = __shfl_up(x, off, 64);
        if (lane >= off) x += y;
    }
    if (lane == 63) wsum[wid] = x;
    __syncthreads();
    if (wid == 0 && lane < 16) {
        int w = wsum[lane];
#pragma unroll
        for (int off = 1; off < 16; off <<= 1) {
            int y = __shfl_up(w, off, 16);
            if (lane >= off) w += y;
        }
        wsum[lane] = w;
    }
    __syncthreads();
    int excl = x - v + ((wid > 0) ? wsum[wid - 1] : 0);
    if (gi < n) row_start[gi] = excl;
    if (tid == 1023) partials[blockIdx.x] = wsum[15];
}

__global__ void scan_partials(int* __restrict__ partials, int nb) {
    int lane = threadIdx.x;  // 64 threads, nb <= 64
    int v = (lane < nb) ? partials[lane] : 0;
    int x = v;
#pragma unroll
    for (int off = 1; off < 64; off <<= 1) {
        int y = __shfl_up(x, off, 64);
        if (lane >= off) x += y;
    }
    if (lane < nb) partials[lane] = x - v;
    if (lane == nb - 1) partials[nb] = x;
}

__global__ __launch_bounds__(1024) void scan_add(int* __restrict__ row_start,
                                                 const int* __restrict__ partials,
                                                 int n, int nb) {
    int gi = blockIdx.x * 1024 + threadIdx.x;
    if (gi < n) row_start[gi] += partials[blockIdx.x];
    if (gi == 0) row_start[n] = partials[nb];
}

__global__ void scatter_kernel(const int* __restrict__ ei,
                               const int* __restrict__ row_start,
                               int* __restrict__ fill,
                               int2* __restrict__ edge_sd, int E, int Etot) {
    int e = blockIdx.x * blockDim.x + threadIdx.x;
    if (e >= Etot) return;
    int src, dst;
    if (e < E) { src = ei[e]; dst = ei[E + e]; }
    else       { src = e - E; dst = e - E; }
    int pos = row_start[dst] + atomicAdd(&fill[dst], 1);
    edge_sd[pos] = make_int2(src, dst);
}

// per-layer: rec[i] = {src, w0|w1, w2|w3, pad}, w = exp(leaky(a_s+a_d)) fp16
__global__ void fill_rec(const int2* __restrict__ edge_sd,
                         const __half* __restrict__ a_s_h,
                         const float* __restrict__ a_d,
                         uint4* __restrict__ rec, int Etot) {
    int i = blockIdx.x * blockDim.x + threadIdx.x;
    if (i >= Etot) return;
    int2 sd = edge_sd[i];
    uint2 as2 = *(const uint2*)&a_s_h[(size_t)sd.x * 4];
    float4 ad4 = *(const float4*)&a_d[(size_t)sd.y * 4];
    float2 f01 = __half22float2(*(const __half2*)&as2.x);
    float2 f23 = __half22float2(*(const __half2*)&as2.y);
    float e0 = f01.x + ad4.x, e1 = f01.y + ad4.y;
    float e2 = f23.x + ad4.z, e3 = f23.y + ad4.w;
    e0 = (e0 > 0.f) ? e0 : LEAKY_SLOPE * e0;
    e1 = (e1 > 0.f) ? e1 : LEAKY_SLOPE * e1;
    e2 = (e2 > 0.f) ? e2 : LEAKY_SLOPE * e2;
    e3 = (e3 > 0.f) ? e3 : LEAKY_SLOPE * e3;
    __half2 w01 = __floats2half2_rn(__expf(e0), __expf(e1));
    __half2 w23 = __floats2half2_rn(__expf(e2), __expf(e3));
    uint4 r = {(unsigned)sd.x, *(unsigned*)&w01, *(unsigned*)&w23, 0u};
    rec[i] = r;
}

// ---------------- split-bf16 helpers ----------------

__device__ __forceinline__ short bf16_rne(float f) {
    unsigned u = __float_as_uint(f);
    return (short)((u + 0x7FFFu + ((u >> 16) & 1u)) >> 16);
}

__device__ __forceinline__ void split_bf16(float f, short& hi, short& lo) {
    unsigned u = __float_as_uint(f);
    hi = (short)(u >> 16);
    float fhi = __uint_as_float(u & 0xFFFF0000u);
    float flo = f - fhi;  // exact
    lo = (short)(__float_as_uint(flo) >> 16);
}

// both weight matrices -> transposed bf16 hi/lo tables, single launch
__global__ void split_B2(const float* __restrict__ W1, short* __restrict__ Bt1h,
                         short* __restrict__ Bt1l, const float* __restrict__ W2,
                         short* __restrict__ Bt2h, short* __restrict__ Bt2l) {
    int idx = blockIdx.x * 256 + threadIdx.x;
    if (idx < 128 * 256) {
        int k = idx >> 8, c = idx & 255;
        short hi, lo;
        split_bf16(W1[idx], hi, lo);
        Bt1h[c * 128 + k] = hi;
        Bt1l[c * 128 + k] = lo;
    } else {
        int j = idx - 128 * 256;
        int k = j >> 8, c = j & 255;
        short hi, lo;
        split_bf16(W2[j], hi, lo);
        Bt2h[c * 256 + k] = hi;
        Bt2l[c * 256 + k] = lo;
    }
}

// ---------------- split-bf16 MFMA GEMM + fused attention dots ---------------
// C[M,256] = A[M,K] @ B[K,256], C stored fp16. A fp32 (rne) or bf16.
// 2-term: A_hi(rne) * (B_hi + B_lo). 128x128 tile, BK=32, 2x2 waves.

template <int K, bool ABF16>
__global__ __launch_bounds__(256) void gemm_mfma(
    const void* __restrict__ Ap, const short* __restrict__ Bt_hi,
    const short* __restrict__ Bt_lo, __half* __restrict__ Ch,
    const float* __restrict__ att_src, const float* __restrict__ att_dst,
    __half* __restrict__ a_s_out, float* __restrict__ a_d_out, int M) {
    __shared__ short As_hi[128][40];   // [m][k], pad 32->40
    __shared__ short Bs_hi[128][40];   // [n][k] (transposed)
    __shared__ short Bs_lo[128][40];

    const int col0 = (blockIdx.x & 1) * 128;
    const int row0 = (blockIdx.x >> 1) * 128;
    const int tid = threadIdx.x;
    const int lane = tid & 63;
    const int wave = tid >> 6;
    const int wr = wave >> 1, wc = wave & 1;
    const int quad = lane >> 4, lc = lane & 15;

    float4v acc[4][4] = {};

    for (int k0 = 0; k0 < K; k0 += 32) {
        if constexpr (ABF16) {
            const short* Abf = (const short*)Ap;
#pragma unroll
            for (int i = 0; i < 2; i++) {
                int slot = tid + i * 256;       // 0..511
                int r = slot >> 2;              // 0..127
                int ko = (slot & 3) * 8;        // 0,8,16,24
                short8v v = {};
                int gr = row0 + r;
                if (gr < M) v = *(const short8v*)&Abf[(size_t)gr * K + k0 + ko];
                *(short8v*)&As_hi[r][ko] = v;
            }
        } else {
            const float* A = (const float*)Ap;
#pragma unroll
            for (int i = 0; i < 4; i++) {
                int slot = tid + i * 256;
                int r = slot >> 3;
                int kq = (slot & 7) * 4;
                float4 v = {0.f, 0.f, 0.f, 0.f};
                int gr = row0 + r;
                if (gr < M) v = *(const float4*)&A[(size_t)gr * K + k0 + kq];
                short4 h4;
                h4.x = bf16_rne(v.x); h4.y = bf16_rne(v.y);
                h4.z = bf16_rne(v.z); h4.w = bf16_rne(v.w);
                *(short4*)&As_hi[r][kq] = h4;
            }
        }
        // B staging: pure 16B vector loads from pre-split transposed tables
#pragma unroll
        for (int i = 0; i < 2; i++) {
            int slot = tid + i * 256;
            int r = slot >> 2;                  // col within tile 0..127
            int ko = (slot & 3) * 8;
            size_t gb = (size_t)(col0 + r) * K + k0 + ko;
            short8v vh = *(const short8v*)&Bt_hi[gb];
            short8v vl = *(const short8v*)&Bt_lo[gb];
            *(short8v*)&Bs_hi[r][ko] = vh;
            *(short8v*)&Bs_lo[r][ko] = vl;
        }
        __syncthreads();

        short8v a_hi[4], b_hi[4], b_lo[4];
#pragma unroll
        for (int mt = 0; mt < 4; mt++) {
            int r = wr * 64 + mt * 16 + lc;
            a_hi[mt] = *(const short8v*)&As_hi[r][quad * 8];
        }
#pragma unroll
        for (int nt = 0; nt < 4; nt++) {
            int n = wc * 64 + nt * 16 + lc;
            b_hi[nt] = *(const short8v*)&Bs_hi[n][quad * 8];
            b_lo[nt] = *(const short8v*)&Bs_lo[n][quad * 8];
        }
#pragma unroll
        for (int mt = 0; mt < 4; mt++)
#pragma unroll
            for (int nt = 0; nt < 4; nt++) {
                acc[mt][nt] = __builtin_amdgcn_mfma_f32_16x16x32_bf16(
                    a_hi[mt], b_hi[nt], acc[mt][nt], 0, 0, 0);
                acc[mt][nt] = __builtin_amdgcn_mfma_f32_16x16x32_bf16(
                    a_hi[mt], b_lo[nt], acc[mt][nt], 0, 0, 0);
            }
        __syncthreads();
    }

    // ---- epilogue: wave's 64 cols = head; C/D: col=lc(+nt*16), row=quad*4+r
    const int head = (col0 >> 6) + wc;
    float as_c[4], ad_c[4];
#pragma unroll
    for (int nt = 0; nt < 4; nt++) {
        as_c[nt] = att_src[head * 64 + nt * 16 + lc];
        ad_c[nt] = att_dst[head * 64 + nt * 16 + lc];
    }

#pragma unroll
    for (int mt = 0; mt < 4; mt++) {
#pragma unroll
        for (int r = 0; r < 4; r++) {
            int gr = row0 + wr * 64 + mt * 16 + quad * 4 + r;
            float ps = 0.f, pd = 0.f;
#pragma unroll
            for (int nt = 0; nt < 4; nt++) {
                float c = acc[mt][nt][r];
                ps = fmaf(c, as_c[nt], ps);
                pd = fmaf(c, ad_c[nt], pd);
                if (gr < M)
                    Ch[(size_t)gr * 256 + col0 + wc * 64 + nt * 16 + lc] =
                        __float2half(c);
            }
#pragma unroll
            for (int off = 1; off < 16; off <<= 1) {
                ps += __shfl_xor(ps, off, 64);
                pd += __shfl_xor(pd, off, 64);
            }
            if (lc == 0 && gr < M) {
                a_s_out[gr * 4 + head] = __float2half(ps);
                a_d_out[gr * 4 + head] = pd;
            }
        }
    }
}

// ---------------- fused aggregate + bias + elu ----------------
// 1 node/wave, 2 edges/iteration: lanes 0-31 = edge p, lanes 32-63 = edge
// p+1 (16B/lane -> one 1KB gather instruction per pair). Wave-uniform loop,
// depth-3 rotation-free pipeline. Odd tail: w forced to 0 via cndmask.
// Epilogue: cross-half shfl_xor(32) reduce; half 0 stores.

template <bool OUT_BF16>
__global__ __launch_bounds__(256) void gat_aggregate(
    const __half* __restrict__ hh, const uint4* __restrict__ rec,
    const int* __restrict__ row_start, const float* __restrict__ bias,
    void* __restrict__ outp, int n) {
    int node = (blockIdx.x * blockDim.x + threadIdx.x) >> 6;
    if (node >= n) return;                 // wave-uniform
    int lane = threadIdx.x & 63;
    int half = lane >> 5, l32 = lane & 31;
    int head = l32 >> 3;

    int beg = row_start[node];
    int end = row_start[node + 1];
    int em1 = end - 1;                     // degree >= 1 (self-loops)

    float l = 0.f;
    float acc[8] = {};

    // pair-iteration i covers edges beg+2i (half 0) and beg+2i+1 (half 1)
    uint4 r0 = rec[min(beg + half, em1)];
    uint4 r1 = rec[min(beg + 2 + half, em1)];
    uint4 r2 = rec[min(beg + 4 + half, em1)];

#define GATH(rr) (*(const uint4*)&hh[(size_t)(rr).x * 256 + l32 * 8])
#define PROC(rr, vv, pp)                                                  \
    {                                                                     \
        unsigned u = (head & 2) ? (rr).z : (rr).y;                        \
        unsigned short us = (head & 1) ? (unsigned short)(u >> 16)        \
                                       : (unsigned short)(u & 0xFFFFu);   \
        float w = __half2float(*(const __half*)&us);                      \
        w = ((pp) + half < end) ? w : 0.f;                                \
        l += w;                                                           \
        const __half2* hp = (const __half2*)&(vv);                        \
        float2 f0 = __half22float2(hp[0]);                                \
        float2 f1 = __half22float2(hp[1]);                                \
        float2 f2 = __half22float2(hp[2]);                                \
        float2 f3 = __half22float2(hp[3]);                                \
        acc[0] = fmaf(w, f0.x, acc[0]); acc[1] = fmaf(w, f0.y, acc[1]);   \
        acc[2] = fmaf(w, f1.x, acc[2]); acc[3] = fmaf(w, f1.y, acc[3]);   \
        acc[4] = fmaf(w, f2.x, acc[4]); acc[5] = fmaf(w, f2.y, acc[5]);   \
        acc[6] = fmaf(w, f3.x, acc[6]); acc[7] = fmaf(w, f3.y, acc[7]);   \
    }

    uint4 h0 = GATH(r0);
    uint4 h1 = GATH(r1);
    uint4 h2;

    int p = beg;
    while (p < end) {
        // k = 0 : pair at p
        h2 = GATH(r2);
        PROC(r0, h0, p);
        r0 = rec[min(p + 6 + half, em1)];
        p += 2;
        if (p >= end) break;
        // k = 1
        h0 = GATH(r0);
        PROC(r1, h1, p);
        r1 = rec[min(p + 6 + half, em1)];
        p += 2;
        if (p >= end) break;
        // k = 2
        h1 = GATH(r1);
        PROC(r2, h2, p);
        r2 = rec[min(p + 6 + half, em1)];
        p += 2;
    }
#undef GATH
#undef PROC

    // combine the two halves (same node, disjoint edges, same channels)
    l += __shfl_xor(l, 32);
#pragma unroll
    for (int j = 0; j < 8; j++) acc[j] += __shfl_xor(acc[j], 32);

    if (half == 0) {
        float rcp = 1.f / l;
        float4 b0 = *(const float4*)&bias[l32 * 8];
        float4 b1 = *(const float4*)&bias[l32 * 8 + 4];
        float o[8];
        o[0] = fmaf(acc[0], rcp, b0.x); o[1] = fmaf(acc[1], rcp, b0.y);
        o[2] = fmaf(acc[2], rcp, b0.z); o[3] = fmaf(acc[3], rcp, b0.w);
        o[4] = fmaf(acc[4], rcp, b1.x); o[5] = fmaf(acc[5], rcp, b1.y);
        o[6] = fmaf(acc[6], rcp, b1.z); o[7] = fmaf(acc[7], rcp, b1.w);
#pragma unroll
        for (int j = 0; j < 8; j++)
            o[j] = (o[j] > 0.f) ? o[j] : __expf(o[j]) - 1.f;
        if constexpr (OUT_BF16) {
            short ob[8];
#pragma unroll
            for (int j = 0; j < 8; j++) ob[j] = bf16_rne(o[j]);
            short* outb = (short*)outp;
            *(short4*)&outb[(size_t)node * 256 + l32 * 8] = *(short4*)&ob[0];
            *(short4*)&outb[(size_t)node * 256 + l32 * 8 + 4] = *(short4*)&ob[4];
        } else {
            float* outf = (float*)outp;
            *(float4*)&outf[(size_t)node * 256 + l32 * 8] = *(float4*)&o[0];
            *(float4*)&outf[(size_t)node * 256 + l32 * 8 + 4] = *(float4*)&o[4];
        }
    }
}

// ---------------- launch ----------------

extern "C" void kernel_launch(void* const* d_in, const int* in_sizes, int n_in,
                              void* d_out, int out_size, void* d_ws, size_t ws_size,
                              hipStream_t stream) {
    const float* x   = (const float*)d_in[0];
    const int*   ei  = (const int*)d_in[1];
    const float* W1  = (const float*)d_in[2];
    const float* as1 = (const float*)d_in[3];
    const float* ad1 = (const float*)d_in[4];
    const float* b1  = (const float*)d_in[5];
    const float* W2  = (const float*)d_in[6];
    const float* as2 = (const float*)d_in[7];
    const float* ad2 = (const float*)d_in[8];
    const float* b2  = (const float*)d_in[9];
    float* out = (float*)d_out;

    const int N = in_sizes[0] / 128;
    const int E = in_sizes[1] / 2;
    const int Etot = E + N;
    const int NB = (N + 1023) / 1024;   // scan blocks (<= 64)

    // workspace layout (16B-aligned segments first)
    __half* h_half = (__half*)d_ws;                        // N*256 fp16
    short*  x1_bf  = (short*)(h_half + (size_t)N * 256);   // N*256 bf16
    uint4*  rec    = (uint4*)(x1_bf + (size_t)N * 256);    // Etot x 16B
    __half* a_s_h  = (__half*)(rec + Etot);                // N*4 fp16
    float*  a_d    = (float*)(a_s_h + (size_t)N * 4);      // N*4 fp32
    short*  Bt1h   = (short*)(a_d + (size_t)N * 4);        // 256*128 bf16
    short*  Bt1l   = Bt1h + 256 * 128;
    short*  Bt2h   = Bt1l + 256 * 128;                     // 256*256 bf16
    short*  Bt2l   = Bt2h + 256 * 256;
    int*    cnt    = (int*)(Bt2l + 256 * 256);             // N
    int*    fill   = cnt + N;                              // N
    int*    row_st = fill + N;                             // N+2 (pad for align)
    int2*   edge_sd = (int2*)(row_st + (N + 2));           // Etot x 8B
    int*    partials = (int*)(edge_sd + Etot);             // NB+1

    // pre-split both weight matrices (one launch, independent of the rest)
    split_B2<<<384, 256, 0, stream>>>(W1, Bt1h, Bt1l, W2, Bt2h, Bt2l);

    hipMemsetAsync(cnt, 0, sizeof(int) * 2 * (size_t)N, stream);  // cnt + fill
    int eblocks = (Etot + 255) / 256;
    hist_kernel<<<eblocks, 256, 0, stream>>>(ei, cnt, E, Etot);
    scan_block<<<NB, 1024, 0, stream>>>(cnt, row_st, partials, N);
    scan_partials<<<1, 64, 0, stream>>>(partials, NB);
    scan_add<<<NB, 1024, 0, stream>>>(row_st, partials, N, NB);
    scatter_kernel<<<eblocks, 256, 0, stream>>>(ei, row_st, fill, edge_sd, E, Etot);

    dim3 ggrid(2 * ((N + 127) / 128));
    int ablocks = (N + 3) / 4;   // 4 nodes (waves) per 256-thread block

    // layer 1
    gemm_mfma<128, false><<<ggrid, 256, 0, stream>>>(x, Bt1h, Bt1l, h_half,
                                                     as1, ad1, a_s_h, a_d, N);
    fill_rec<<<eblocks, 256, 0, stream>>>(edge_sd, a_s_h, a_d, rec, Etot);
    gat_aggregate<true><<<ablocks, 256, 0, stream>>>(h_half, rec, row_st,
                                                     b1, x1_bf, N);
    // layer 2
    gemm_mfma<256, true><<<ggrid, 256, 0, stream>>>(x1_bf, Bt2h, Bt2l, h_half,
                                                    as2, ad2, a_s_h, a_d, N);
    fill_rec<<<eblocks, 256, 0, stream>>>(edge_sd, a_s_h, a_d, rec, Etot);
    gat_aggregate<false><<<ablocks, 256, 0, stream>>>(h_half, rec, row_st,
                                                      b2, out, N);
}

// Round 3
// 400.800 us; speedup vs baseline: 1.0494x; 1.0032x over previous
//
#include <hip/hip_runtime.h>
#include <hip/hip_fp16.h>
#include <math.h>

// ---------------------------------------------------------------------------
// GAT encoder, 2 layers.
//   GEMMs: 2-term split-bf16 MFMA (A_hi(rne)*B_hi + A_hi*B_lo). B pre-split
//          once into transposed bf16 hi/lo tables; x pre-converted to bf16
//          (stored in the x1 buffer, dead until aggregate-1 writes it) so
//          both GEMMs use the pure 16B-load A-staging path.
//   Padded CSR: per-node degree rounded up to even; holes carry sentinel
//          records (src=0, w=0) so the aggregate inner loop has NO clamps
//          and NO tail checks.
//   fill_rec computes softmax weight w = exp(leaky(a_s[src]+a_d[dst])) per
//          edge per head; rec[i] = {src, w0|w1, w2|w3, 0} (fp16 weights);
//          writes zero-records for holes (edge_sd memset to 0xFF).
//   Aggregation: 1 node/wave, 2 edges/iteration (lanes 0-31 edge p, lanes
//          32-63 edge p+1; 16B/lane -> one 1KB gather per pair), depth-4
//          rotation-free software pipeline, prefetch distance 8 edges.
// ---------------------------------------------------------------------------

#define LEAKY_SLOPE 0.2f

typedef __attribute__((ext_vector_type(8))) short short8v;   // 8 bf16
typedef __attribute__((ext_vector_type(4))) float float4v;

// ---------------- helpers ----------------

__device__ __forceinline__ short bf16_rne(float f) {
    unsigned u = __float_as_uint(f);
    return (short)((u + 0x7FFFu + ((u >> 16) & 1u)) >> 16);
}

__device__ __forceinline__ void split_bf16(float f, short& hi, short& lo) {
    unsigned u = __float_as_uint(f);
    hi = (short)(u >> 16);
    float fhi = __uint_as_float(u & 0xFFFF0000u);
    float flo = f - fhi;  // exact
    lo = (short)(__float_as_uint(flo) >> 16);
}

// ---------------- fused prep: W splits + x->bf16 + degree histogram --------

__global__ void prep_kernel(const float* __restrict__ W1, short* __restrict__ Bt1h,
                            short* __restrict__ Bt1l, const float* __restrict__ W2,
                            short* __restrict__ Bt2h, short* __restrict__ Bt2l,
                            const float* __restrict__ x, short* __restrict__ x_bf,
                            const int* __restrict__ ei, int* __restrict__ cnt,
                            int E, int N, int xblocks) {
    int b = blockIdx.x;
    if (b < 128) {                       // W1 split: 128*256 elems
        int idx = b * 256 + threadIdx.x;
        int k = idx >> 8, c = idx & 255;
        short hi, lo;
        split_bf16(W1[idx], hi, lo);
        Bt1h[c * 128 + k] = hi;
        Bt1l[c * 128 + k] = lo;
    } else if (b < 384) {                // W2 split: 256*256 elems
        int idx = (b - 128) * 256 + threadIdx.x;
        int k = idx >> 8, c = idx & 255;
        short hi, lo;
        split_bf16(W2[idx], hi, lo);
        Bt2h[c * 256 + k] = hi;
        Bt2l[c * 256 + k] = lo;
    } else if (b < 384 + xblocks) {      // x -> bf16 (rne), 4 elems/thread
        int t = (b - 384) * 256 + threadIdx.x;
        if (t < N * 32) {
            float4 v = *(const float4*)&x[(size_t)t * 4];
            short4 h4;
            h4.x = bf16_rne(v.x); h4.y = bf16_rne(v.y);
            h4.z = bf16_rne(v.z); h4.w = bf16_rne(v.w);
            *(short4*)&x_bf[(size_t)t * 4] = h4;
        }
    } else {                             // degree histogram (incl. self-loops)
        int e = (b - 384 - xblocks) * 256 + threadIdx.x;
        if (e < E + N) {
            int dst = (e < E) ? ei[E + e] : (e - E);
            atomicAdd(&cnt[dst], 1);
        }
    }
}

// ---------------- CSR build (padded to even degree) ----------------

__global__ __launch_bounds__(1024) void scan_block(const int* __restrict__ cnt,
                                                   int* __restrict__ row_start,
                                                   int* __restrict__ partials,
                                                   int n) {
    __shared__ int wsum[16];
    int tid = threadIdx.x, lane = tid & 63, wid = tid >> 6;
    int gi = blockIdx.x * 1024 + tid;
    int v = (gi < n) ? ((cnt[gi] + 1) & ~1) : 0;   // pad degree to even
    int x = v;
#pragma unroll
    for (int off = 1; off < 64; off <<= 1) {
        int y = __shfl_up(x, off, 64);
        if (lane >= off) x += y;
    }
    if (lane == 63) wsum[wid] = x;
    __syncthreads();
    if (wid == 0 && lane < 16) {
        int w = wsum[lane];
#pragma unroll
        for (int off = 1; off < 16; off <<= 1) {
            int y = __shfl_up(w, off, 16);
            if (lane >= off) w += y;
        }
        wsum[lane] = w;
    }
    __syncthreads();
    int excl = x - v + ((wid > 0) ? wsum[wid - 1] : 0);
    if (gi < n) row_start[gi] = excl;
    if (tid == 1023) partials[blockIdx.x] = wsum[15];
}

__global__ void scan_partials(int* __restrict__ partials, int nb) {
    int lane = threadIdx.x;  // 64 threads, nb <= 64
    int v = (lane < nb) ? partials[lane] : 0;
    int x = v;
#pragma unroll
    for (int off = 1; off < 64; off <<= 1) {
        int y = __shfl_up(x, off, 64);
        if (lane >= off) x += y;
    }
    if (lane < nb) partials[lane] = x - v;
    if (lane == nb - 1) partials[nb] = x;
}

__global__ __launch_bounds__(1024) void scan_add(int* __restrict__ row_start,
                                                 const int* __restrict__ partials,
                                                 int n, int nb) {
    int gi = blockIdx.x * 1024 + threadIdx.x;
    if (gi < n) row_start[gi] += partials[blockIdx.x];
    if (gi == 0) row_start[n] = partials[nb];
}

__global__ void scatter_kernel(const int* __restrict__ ei,
                               const int* __restrict__ row_start,
                               int* __restrict__ fill,
                               int2* __restrict__ edge_sd, int E, int Etot) {
    int e = blockIdx.x * blockDim.x + threadIdx.x;
    if (e >= Etot) return;
    int src, dst;
    if (e < E) { src = ei[e]; dst = ei[E + e]; }
    else       { src = e - E; dst = e - E; }
    int pos = row_start[dst] + atomicAdd(&fill[dst], 1);
    edge_sd[pos] = make_int2(src, dst);
}

// rec[i] = {src, w0|w1, w2|w3, pad}, w = exp(leaky(a_s+a_d)) fp16.
// Sentinel slots (edge_sd memset 0xFF) -> zero record (w=0, src=0).
__global__ void fill_rec(const int2* __restrict__ edge_sd,
                         const __half* __restrict__ a_s_h,
                         const float* __restrict__ a_d,
                         uint4* __restrict__ rec, int EtotMax) {
    int i = blockIdx.x * blockDim.x + threadIdx.x;
    if (i >= EtotMax) return;
    int2 sd = edge_sd[i];
    if (sd.x < 0) {                      // hole / pad slot
        uint4 z = {0u, 0u, 0u, 0u};
        rec[i] = z;
        return;
    }
    uint2 as2 = *(const uint2*)&a_s_h[(size_t)sd.x * 4];
    float4 ad4 = *(const float4*)&a_d[(size_t)sd.y * 4];
    float2 f01 = __half22float2(*(const __half2*)&as2.x);
    float2 f23 = __half22float2(*(const __half2*)&as2.y);
    float e0 = f01.x + ad4.x, e1 = f01.y + ad4.y;
    float e2 = f23.x + ad4.z, e3 = f23.y + ad4.w;
    e0 = (e0 > 0.f) ? e0 : LEAKY_SLOPE * e0;
    e1 = (e1 > 0.f) ? e1 : LEAKY_SLOPE * e1;
    e2 = (e2 > 0.f) ? e2 : LEAKY_SLOPE * e2;
    e3 = (e3 > 0.f) ? e3 : LEAKY_SLOPE * e3;
    __half2 w01 = __floats2half2_rn(__expf(e0), __expf(e1));
    __half2 w23 = __floats2half2_rn(__expf(e2), __expf(e3));
    uint4 r = {(unsigned)sd.x, *(unsigned*)&w01, *(unsigned*)&w23, 0u};
    rec[i] = r;
}

// ---------------- split-bf16 MFMA GEMM + fused attention dots ---------------
// C[M,256] = A[M,K] @ B[K,256], C stored fp16. A bf16 (pre-converted).
// 2-term: A_hi(rne) * (B_hi + B_lo). 128x128 tile, BK=32, 2x2 waves.

template <int K>
__global__ __launch_bounds__(256) void gemm_mfma(
    const short* __restrict__ Abf, const short* __restrict__ Bt_hi,
    const short* __restrict__ Bt_lo, __half* __restrict__ Ch,
    const float* __restrict__ att_src, const float* __restrict__ att_dst,
    __half* __restrict__ a_s_out, float* __restrict__ a_d_out, int M) {
    __shared__ short As_hi[128][40];   // [m][k], pad 32->40
    __shared__ short Bs_hi[128][40];   // [n][k] (transposed)
    __shared__ short Bs_lo[128][40];

    const int col0 = (blockIdx.x & 1) * 128;
    const int row0 = (blockIdx.x >> 1) * 128;
    const int tid = threadIdx.x;
    const int lane = tid & 63;
    const int wave = tid >> 6;
    const int wr = wave >> 1, wc = wave & 1;
    const int quad = lane >> 4, lc = lane & 15;

    float4v acc[4][4] = {};

    for (int k0 = 0; k0 < K; k0 += 32) {
#pragma unroll
        for (int i = 0; i < 2; i++) {
            int slot = tid + i * 256;       // 0..511
            int r = slot >> 2;              // 0..127
            int ko = (slot & 3) * 8;        // 0,8,16,24
            short8v v = {};
            int gr = row0 + r;
            if (gr < M) v = *(const short8v*)&Abf[(size_t)gr * K + k0 + ko];
            *(short8v*)&As_hi[r][ko] = v;
        }
        // B staging: pure 16B vector loads from pre-split transposed tables
#pragma unroll
        for (int i = 0; i < 2; i++) {
            int slot = tid + i * 256;
            int r = slot >> 2;                  // col within tile 0..127
            int ko = (slot & 3) * 8;
            size_t gb = (size_t)(col0 + r) * K + k0 + ko;
            short8v vh = *(const short8v*)&Bt_hi[gb];
            short8v vl = *(const short8v*)&Bt_lo[gb];
            *(short8v*)&Bs_hi[r][ko] = vh;
            *(short8v*)&Bs_lo[r][ko] = vl;
        }
        __syncthreads();

        short8v a_hi[4], b_hi[4], b_lo[4];
#pragma unroll
        for (int mt = 0; mt < 4; mt++) {
            int r = wr * 64 + mt * 16 + lc;
            a_hi[mt] = *(const short8v*)&As_hi[r][quad * 8];
        }
#pragma unroll
        for (int nt = 0; nt < 4; nt++) {
            int n = wc * 64 + nt * 16 + lc;
            b_hi[nt] = *(const short8v*)&Bs_hi[n][quad * 8];
            b_lo[nt] = *(const short8v*)&Bs_lo[n][quad * 8];
        }
#pragma unroll
        for (int mt = 0; mt < 4; mt++)
#pragma unroll
            for (int nt = 0; nt < 4; nt++) {
                acc[mt][nt] = __builtin_amdgcn_mfma_f32_16x16x32_bf16(
                    a_hi[mt], b_hi[nt], acc[mt][nt], 0, 0, 0);
                acc[mt][nt] = __builtin_amdgcn_mfma_f32_16x16x32_bf16(
                    a_hi[mt], b_lo[nt], acc[mt][nt], 0, 0, 0);
            }
        __syncthreads();
    }

    // ---- epilogue: wave's 64 cols = head; C/D: col=lc(+nt*16), row=quad*4+r
    const int head = (col0 >> 6) + wc;
    float as_c[4], ad_c[4];
#pragma unroll
    for (int nt = 0; nt < 4; nt++) {
        as_c[nt] = att_src[head * 64 + nt * 16 + lc];
        ad_c[nt] = att_dst[head * 64 + nt * 16 + lc];
    }

#pragma unroll
    for (int mt = 0; mt < 4; mt++) {
#pragma unroll
        for (int r = 0; r < 4; r++) {
            int gr = row0 + wr * 64 + mt * 16 + quad * 4 + r;
            float ps = 0.f, pd = 0.f;
#pragma unroll
            for (int nt = 0; nt < 4; nt++) {
                float c = acc[mt][nt][r];
                ps = fmaf(c, as_c[nt], ps);
                pd = fmaf(c, ad_c[nt], pd);
                if (gr < M)
                    Ch[(size_t)gr * 256 + col0 + wc * 64 + nt * 16 + lc] =
                        __float2half(c);
            }
#pragma unroll
            for (int off = 1; off < 16; off <<= 1) {
                ps += __shfl_xor(ps, off, 64);
                pd += __shfl_xor(pd, off, 64);
            }
            if (lc == 0 && gr < M) {
                a_s_out[gr * 4 + head] = __float2half(ps);
                a_d_out[gr * 4 + head] = pd;
            }
        }
    }
}

// ---------------- fused aggregate + bias + elu ----------------
// 1 node/wave, 2 edges/iteration, padded-even rows: no clamps, no tail
// checks. Depth-4 rotation-free pipeline, prefetch distance 8 edges.

template <bool OUT_BF16>
__global__ __launch_bounds__(256) void gat_aggregate(
    const __half* __restrict__ hh, const uint4* __restrict__ rec,
    const int* __restrict__ row_start, const float* __restrict__ bias,
    void* __restrict__ outp, int n) {
    int node = (blockIdx.x * blockDim.x + threadIdx.x) >> 6;
    if (node >= n) return;                 // wave-uniform
    int lane = threadIdx.x & 63;
    int half = lane >> 5, l32 = lane & 31;
    int head = l32 >> 3;
    unsigned wsh = (head & 1) << 4;        // 16-bit select shift, hoisted

    int beg = row_start[node];
    int end = row_start[node + 1];         // end-beg even, >= 2

    float l = 0.f;
    float acc[8] = {};

    uint4 r0 = rec[beg + half];
    uint4 r1 = rec[beg + 2 + half];
    uint4 r2 = rec[beg + 4 + half];
    uint4 r3 = rec[beg + 6 + half];

#define GATH(rr) (*(const uint4*)&hh[(size_t)(rr).x * 256 + l32 * 8])
#define PROC(rr, vv)                                                      \
    {                                                                     \
        unsigned u = (head & 2) ? (rr).z : (rr).y;                        \
        unsigned short us = (unsigned short)(u >> wsh);                   \
        float w = __half2float(*(const __half*)&us);                      \
        l += w;                                                           \
        const __half2* hp = (const __half2*)&(vv);                        \
        float2 f0 = __half22float2(hp[0]);                                \
        float2 f1 = __half22float2(hp[1]);                                \
        float2 f2 = __half22float2(hp[2]);                                \
        float2 f3 = __half22float2(hp[3]);                                \
        acc[0] = fmaf(w, f0.x, acc[0]); acc[1] = fmaf(w, f0.y, acc[1]);   \
        acc[2] = fmaf(w, f1.x, acc[2]); acc[3] = fmaf(w, f1.y, acc[3]);   \
        acc[4] = fmaf(w, f2.x, acc[4]); acc[5] = fmaf(w, f2.y, acc[5]);   \
        acc[6] = fmaf(w, f3.x, acc[6]); acc[7] = fmaf(w, f3.y, acc[7]);   \
    }

    uint4 h0 = GATH(r0);
    uint4 h1 = GATH(r1);
    uint4 h2 = GATH(r2);
    uint4 h3;

    int p = beg;
    while (p < end) {
        // phase 0 : pair at p
        h3 = GATH(r3);
        PROC(r0, h0);
        r0 = rec[p + 8 + half];
        p += 2;
        if (p >= end) break;
        // phase 1
        h0 = GATH(r0);
        PROC(r1, h1);
        r1 = rec[p + 8 + half];
        p += 2;
        if (p >= end) break;
        // phase 2
        h1 = GATH(r1);
        PROC(r2, h2);
        r2 = rec[p + 8 + half];
        p += 2;
        if (p >= end) break;
        // phase 3
        h2 = GATH(r2);
        PROC(r3, h3);
        r3 = rec[p + 8 + half];
        p += 2;
    }
#undef GATH
#undef PROC

    // combine the two halves (same node, disjoint edges, same channels)
    l += __shfl_xor(l, 32);
#pragma unroll
    for (int j = 0; j < 8; j++) acc[j] += __shfl_xor(acc[j], 32);

    if (half == 0) {
        float rcp = 1.f / l;
        float4 b0 = *(const float4*)&bias[l32 * 8];
        float4 b1 = *(const float4*)&bias[l32 * 8 + 4];
        float o[8];
        o[0] = fmaf(acc[0], rcp, b0.x); o[1] = fmaf(acc[1], rcp, b0.y);
        o[2] = fmaf(acc[2], rcp, b0.z); o[3] = fmaf(acc[3], rcp, b0.w);
        o[4] = fmaf(acc[4], rcp, b1.x); o[5] = fmaf(acc[5], rcp, b1.y);
        o[6] = fmaf(acc[6], rcp, b1.z); o[7] = fmaf(acc[7], rcp, b1.w);
#pragma unroll
        for (int j = 0; j < 8; j++)
            o[j] = (o[j] > 0.f) ? o[j] : __expf(o[j]) - 1.f;
        if constexpr (OUT_BF16) {
            short ob[8];
#pragma unroll
            for (int j = 0; j < 8; j++) ob[j] = bf16_rne(o[j]);
            short* outb = (short*)outp;
            *(short4*)&outb[(size_t)node * 256 + l32 * 8] = *(short4*)&ob[0];
            *(short4*)&outb[(size_t)node * 256 + l32 * 8 + 4] = *(short4*)&ob[4];
        } else {
            float* outf = (float*)outp;
            *(float4*)&outf[(size_t)node * 256 + l32 * 8] = *(float4*)&o[0];
            *(float4*)&outf[(size_t)node * 256 + l32 * 8 + 4] = *(float4*)&o[4];
        }
    }
}

// ---------------- launch ----------------

extern "C" void kernel_launch(void* const* d_in, const int* in_sizes, int n_in,
                              void* d_out, int out_size, void* d_ws, size_t ws_size,
                              hipStream_t stream) {
    const float* x   = (const float*)d_in[0];
    const int*   ei  = (const int*)d_in[1];
    const float* W1  = (const float*)d_in[2];
    const float* as1 = (const float*)d_in[3];
    const float* ad1 = (const float*)d_in[4];
    const float* b1  = (const float*)d_in[5];
    const float* W2  = (const float*)d_in[6];
    const float* as2 = (const float*)d_in[7];
    const float* ad2 = (const float*)d_in[8];
    const float* b2  = (const float*)d_in[9];
    float* out = (float*)d_out;

    const int N = in_sizes[0] / 128;
    const int E = in_sizes[1] / 2;
    const int Etot = E + N;
    const int EtotMax = Etot + N + 8;   // worst-case padded slots + pipeline pad
    const int NB = (N + 1023) / 1024;   // scan blocks (<= 64)

    // workspace layout (16B-aligned segments first)
    __half* h_half = (__half*)d_ws;                        // N*256 fp16
    short*  x1_bf  = (short*)(h_half + (size_t)N * 256);   // N*256 bf16 (also x_bf)
    uint4*  rec    = (uint4*)(x1_bf + (size_t)N * 256);    // EtotMax x 16B
    __half* a_s_h  = (__half*)(rec + EtotMax);             // N*4 fp16
    float*  a_d    = (float*)(a_s_h + (size_t)N * 4);      // N*4 fp32
    short*  Bt1h   = (short*)(a_d + (size_t)N * 4);        // 256*128 bf16
    short*  Bt1l   = Bt1h + 256 * 128;
    short*  Bt2h   = Bt1l + 256 * 128;                     // 256*256 bf16
    short*  Bt2l   = Bt2h + 256 * 256;
    int*    cnt    = (int*)(Bt2l + 256 * 256);             // N
    int*    fill   = cnt + N;                              // N
    int*    row_st = fill + N;                             // N+2 (pad for align)
    int2*   edge_sd = (int2*)(row_st + (N + 2));           // EtotMax x 8B
    int*    partials = (int*)(edge_sd + EtotMax);          // NB+1

    hipMemsetAsync(cnt, 0, sizeof(int) * 2 * (size_t)N, stream);   // cnt + fill
    hipMemsetAsync(edge_sd, 0xFF, sizeof(int2) * (size_t)EtotMax, stream);

    const int xblocks = (N * 32 + 255) / 256;       // x->bf16 blocks
    const int eblocks = (Etot + 255) / 256;         // histogram / scatter blocks
    prep_kernel<<<384 + xblocks + eblocks, 256, 0, stream>>>(
        W1, Bt1h, Bt1l, W2, Bt2h, Bt2l, x, x1_bf, ei, cnt, E, N, xblocks);

    scan_block<<<NB, 1024, 0, stream>>>(cnt, row_st, partials, N);
    scan_partials<<<1, 64, 0, stream>>>(partials, NB);
    scan_add<<<NB, 1024, 0, stream>>>(row_st, partials, N, NB);
    scatter_kernel<<<eblocks, 256, 0, stream>>>(ei, row_st, fill, edge_sd, E, Etot);

    dim3 ggrid(2 * ((N + 127) / 128));
    int ablocks = (N + 3) / 4;          // 4 nodes (waves) per 256-thread block
    int fblocks = (EtotMax + 255) / 256;

    // layer 1 (A = x pre-converted to bf16, living in the x1 buffer)
    gemm_mfma<128><<<ggrid, 256, 0, stream>>>(x1_bf, Bt1h, Bt1l, h_half,
                                              as1, ad1, a_s_h, a_d, N);
    fill_rec<<<fblocks, 256, 0, stream>>>(edge_sd, a_s_h, a_d, rec, EtotMax);
    gat_aggregate<true><<<ablocks, 256, 0, stream>>>(h_half, rec, row_st,
                                                     b1, x1_bf, N);
    // layer 2
    gemm_mfma<256><<<ggrid, 256, 0, stream>>>(x1_bf, Bt2h, Bt2l, h_half,
                                              as2, ad2, a_s_h, a_d, N);
    fill_rec<<<fblocks, 256, 0, stream>>>(edge_sd, a_s_h, a_d, rec, EtotMax);
    gat_aggregate<false><<<ablocks, 256, 0, stream>>>(h_half, rec, row_st,
                                                      b2, out, N);
}

// Round 4
// 387.642 us; speedup vs baseline: 1.0850x; 1.0339x over previous
//
#include <hip/hip_runtime.h>
#include <hip/hip_fp16.h>
#include <math.h>

// ---------------------------------------------------------------------------
// GAT encoder, 2 layers.
//   GEMMs: single-term fp16 MFMA (mfma_f32_16x16x32_f16, fp32 accum).
//          A pre-converted to fp16 (x up-front; x1 written fp16 by
//          aggregate-1); B pre-converted once to a transposed fp16 table.
//          Accuracy >= old 2-term split-bf16 (rel 2^-11 vs 2^-9 A-side).
//   Padded CSR: per-node degree rounded up to even; holes carry sentinel
//          records (src=0, w=0) so the aggregate inner loop has NO clamps
//          and NO tail checks.
//   fill_rec computes softmax weight w = exp(leaky(a_s[src]+a_d[dst])) per
//          edge per head; rec[i] = {src, w0|w1, w2|w3, 0} (fp16 weights).
//   Aggregation: 1 node/wave, 2 edges/iteration (lanes 0-31 edge p, lanes
//          32-63 edge p+1; 16B/lane -> one 1KB gather per pair), depth-4
//          rotation-free software pipeline, prefetch distance 8 edges.
// ---------------------------------------------------------------------------

#define LEAKY_SLOPE 0.2f

typedef __attribute__((ext_vector_type(8))) short short8v;      // 16B
typedef __attribute__((ext_vector_type(8))) _Float16 half8v;    // 8 fp16
typedef __attribute__((ext_vector_type(4))) float float4v;

// ---------------- fused prep: W->fp16 transposed + x->fp16 + histogram -----

__global__ void prep_kernel(const float* __restrict__ W1, __half* __restrict__ Bt1,
                            const float* __restrict__ W2, __half* __restrict__ Bt2,
                            const float* __restrict__ x, __half* __restrict__ x_h,
                            const int* __restrict__ ei, int* __restrict__ cnt,
                            int E, int N, int xblocks) {
    int b = blockIdx.x;
    if (b < 128) {                       // W1: [128][256] -> Bt1[c*128+k]
        int idx = b * 256 + threadIdx.x;
        int k = idx >> 8, c = idx & 255;
        Bt1[c * 128 + k] = __float2half(W1[idx]);
    } else if (b < 384) {                // W2: [256][256] -> Bt2[c*256+k]
        int idx = (b - 128) * 256 + threadIdx.x;
        int k = idx >> 8, c = idx & 255;
        Bt2[c * 256 + k] = __float2half(W2[idx]);
    } else if (b < 384 + xblocks) {      // x -> fp16, 4 elems/thread
        int t = (b - 384) * 256 + threadIdx.x;
        if (t < N * 32) {
            float4 v = *(const float4*)&x[(size_t)t * 4];
            __half2 h01 = __floats2half2_rn(v.x, v.y);
            __half2 h23 = __floats2half2_rn(v.z, v.w);
            uint2 pk = {*(unsigned*)&h01, *(unsigned*)&h23};
            *(uint2*)&x_h[(size_t)t * 4] = pk;
        }
    } else {                             // degree histogram (incl. self-loops)
        int e = (b - 384 - xblocks) * 256 + threadIdx.x;
        if (e < E + N) {
            int dst = (e < E) ? ei[E + e] : (e - E);
            atomicAdd(&cnt[dst], 1);
        }
    }
}

// ---------------- CSR build (padded to even degree) ----------------

__global__ __launch_bounds__(1024) void scan_block(const int* __restrict__ cnt,
                                                   int* __restrict__ row_start,
                                                   int* __restrict__ partials,
                                                   int n) {
    __shared__ int wsum[16];
    int tid = threadIdx.x, lane = tid & 63, wid = tid >> 6;
    int gi = blockIdx.x * 1024 + tid;
    int v = (gi < n) ? ((cnt[gi] + 1) & ~1) : 0;   // pad degree to even
    int x = v;
#pragma unroll
    for (int off = 1; off < 64; off <<= 1) {
        int y = __shfl_up(x, off, 64);
        if (lane >= off) x += y;
    }
    if (lane == 63) wsum[wid] = x;
    __syncthreads();
    if (wid == 0 && lane < 16) {
        int w = wsum[lane];
#pragma unroll
        for (int off = 1; off < 16; off <<= 1) {
            int y = __shfl_up(w, off, 16);
            if (lane >= off) w += y;
        }
        wsum[lane] = w;
    }
    __syncthreads();
    int excl = x - v + ((wid > 0) ? wsum[wid - 1] : 0);
    if (gi < n) row_start[gi] = excl;
    if (tid == 1023) partials[blockIdx.x] = wsum[15];
}

__global__ void scan_partials(int* __restrict__ partials, int nb) {
    int lane = threadIdx.x;  // 64 threads, nb <= 64
    int v = (lane < nb) ? partials[lane] : 0;
    int x = v;
#pragma unroll
    for (int off = 1; off < 64; off <<= 1) {
        int y = __shfl_up(x, off, 64);
        if (lane >= off) x += y;
    }
    if (lane < nb) partials[lane] = x - v;
    if (lane == nb - 1) partials[nb] = x;
}

__global__ __launch_bounds__(1024) void scan_add(int* __restrict__ row_start,
                                                 const int* __restrict__ partials,
                                                 int n, int nb) {
    int gi = blockIdx.x * 1024 + threadIdx.x;
    if (gi < n) row_start[gi] += partials[blockIdx.x];
    if (gi == 0) row_start[n] = partials[nb];
}

__global__ void scatter_kernel(const int* __restrict__ ei,
                               const int* __restrict__ row_start,
                               int* __restrict__ fill,
                               int2* __restrict__ edge_sd, int E, int Etot) {
    int e = blockIdx.x * blockDim.x + threadIdx.x;
    if (e >= Etot) return;
    int src, dst;
    if (e < E) { src = ei[e]; dst = ei[E + e]; }
    else       { src = e - E; dst = e - E; }
    int pos = row_start[dst] + atomicAdd(&fill[dst], 1);
    edge_sd[pos] = make_int2(src, dst);
}

// rec[i] = {src, w0|w1, w2|w3, pad}, w = exp(leaky(a_s+a_d)) fp16.
// Sentinel slots (edge_sd memset 0xFF) -> zero record (w=0, src=0).
__global__ void fill_rec(const int2* __restrict__ edge_sd,
                         const __half* __restrict__ a_s_h,
                         const float* __restrict__ a_d,
                         uint4* __restrict__ rec, int EtotMax) {
    int i = blockIdx.x * blockDim.x + threadIdx.x;
    if (i >= EtotMax) return;
    int2 sd = edge_sd[i];
    if (sd.x < 0) {                      // hole / pad slot
        uint4 z = {0u, 0u, 0u, 0u};
        rec[i] = z;
        return;
    }
    uint2 as2 = *(const uint2*)&a_s_h[(size_t)sd.x * 4];
    float4 ad4 = *(const float4*)&a_d[(size_t)sd.y * 4];
    float2 f01 = __half22float2(*(const __half2*)&as2.x);
    float2 f23 = __half22float2(*(const __half2*)&as2.y);
    float e0 = f01.x + ad4.x, e1 = f01.y + ad4.y;
    float e2 = f23.x + ad4.z, e3 = f23.y + ad4.w;
    e0 = (e0 > 0.f) ? e0 : LEAKY_SLOPE * e0;
    e1 = (e1 > 0.f) ? e1 : LEAKY_SLOPE * e1;
    e2 = (e2 > 0.f) ? e2 : LEAKY_SLOPE * e2;
    e3 = (e3 > 0.f) ? e3 : LEAKY_SLOPE * e3;
    __half2 w01 = __floats2half2_rn(__expf(e0), __expf(e1));
    __half2 w23 = __floats2half2_rn(__expf(e2), __expf(e3));
    uint4 r = {(unsigned)sd.x, *(unsigned*)&w01, *(unsigned*)&w23, 0u};
    rec[i] = r;
}

// ---------------- fp16 MFMA GEMM + fused attention dots ---------------
// C[M,256] = A[M,K] @ B[K,256], C stored fp16. A fp16, B fp16 transposed.
// 128x128 tile, BK=32, 2x2 waves, 16 mfma_f32_16x16x32_f16 per K-step.

template <int K>
__global__ __launch_bounds__(256) void gemm_mfma(
    const __half* __restrict__ Ah, const __half* __restrict__ Bt,
    __half* __restrict__ Ch,
    const float* __restrict__ att_src, const float* __restrict__ att_dst,
    __half* __restrict__ a_s_out, float* __restrict__ a_d_out, int M) {
    __shared__ short As[128][40];   // [m][k], pad 32->40
    __shared__ short Bs[128][40];   // [n][k] (transposed)

    const int col0 = (blockIdx.x & 1) * 128;
    const int row0 = (blockIdx.x >> 1) * 128;
    const int tid = threadIdx.x;
    const int lane = tid & 63;
    const int wave = tid >> 6;
    const int wr = wave >> 1, wc = wave & 1;
    const int quad = lane >> 4, lc = lane & 15;

    float4v acc[4][4] = {};

    const short* Abits = (const short*)Ah;
    const short* Bbits = (const short*)Bt;

    for (int k0 = 0; k0 < K; k0 += 32) {
#pragma unroll
        for (int i = 0; i < 2; i++) {
            int slot = tid + i * 256;       // 0..511
            int r = slot >> 2;              // 0..127
            int ko = (slot & 3) * 8;        // 0,8,16,24
            short8v v = {};
            int gr = row0 + r;
            if (gr < M) v = *(const short8v*)&Abits[(size_t)gr * K + k0 + ko];
            *(short8v*)&As[r][ko] = v;
        }
#pragma unroll
        for (int i = 0; i < 2; i++) {
            int slot = tid + i * 256;
            int r = slot >> 2;              // col within tile 0..127
            int ko = (slot & 3) * 8;
            short8v v = *(const short8v*)&Bbits[(size_t)(col0 + r) * K + k0 + ko];
            *(short8v*)&Bs[r][ko] = v;
        }
        __syncthreads();

        half8v a[4], bv[4];
#pragma unroll
        for (int mt = 0; mt < 4; mt++) {
            int r = wr * 64 + mt * 16 + lc;
            a[mt] = *(const half8v*)&As[r][quad * 8];
        }
#pragma unroll
        for (int nt = 0; nt < 4; nt++) {
            int n = wc * 64 + nt * 16 + lc;
            bv[nt] = *(const half8v*)&Bs[n][quad * 8];
        }
#pragma unroll
        for (int mt = 0; mt < 4; mt++)
#pragma unroll
            for (int nt = 0; nt < 4; nt++)
                acc[mt][nt] = __builtin_amdgcn_mfma_f32_16x16x32_f16(
                    a[mt], bv[nt], acc[mt][nt], 0, 0, 0);
        __syncthreads();
    }

    // ---- epilogue: wave's 64 cols = head; C/D: col=lc(+nt*16), row=quad*4+r
    const int head = (col0 >> 6) + wc;
    float as_c[4], ad_c[4];
#pragma unroll
    for (int nt = 0; nt < 4; nt++) {
        as_c[nt] = att_src[head * 64 + nt * 16 + lc];
        ad_c[nt] = att_dst[head * 64 + nt * 16 + lc];
    }

#pragma unroll
    for (int mt = 0; mt < 4; mt++) {
#pragma unroll
        for (int r = 0; r < 4; r++) {
            int gr = row0 + wr * 64 + mt * 16 + quad * 4 + r;
            float ps = 0.f, pd = 0.f;
#pragma unroll
            for (int nt = 0; nt < 4; nt++) {
                float c = acc[mt][nt][r];
                ps = fmaf(c, as_c[nt], ps);
                pd = fmaf(c, ad_c[nt], pd);
                if (gr < M)
                    Ch[(size_t)gr * 256 + col0 + wc * 64 + nt * 16 + lc] =
                        __float2half(c);
            }
#pragma unroll
            for (int off = 1; off < 16; off <<= 1) {
                ps += __shfl_xor(ps, off, 64);
                pd += __shfl_xor(pd, off, 64);
            }
            if (lc == 0 && gr < M) {
                a_s_out[gr * 4 + head] = __float2half(ps);
                a_d_out[gr * 4 + head] = pd;
            }
        }
    }
}

// ---------------- fused aggregate + bias + elu ----------------
// 1 node/wave, 2 edges/iteration, padded-even rows: no clamps, no tail
// checks. Depth-4 rotation-free pipeline, prefetch distance 8 edges.

template <bool OUT_HALF>
__global__ __launch_bounds__(256) void gat_aggregate(
    const __half* __restrict__ hh, const uint4* __restrict__ rec,
    const int* __restrict__ row_start, const float* __restrict__ bias,
    void* __restrict__ outp, int n) {
    int node = (blockIdx.x * blockDim.x + threadIdx.x) >> 6;
    if (node >= n) return;                 // wave-uniform
    int lane = threadIdx.x & 63;
    int half = lane >> 5, l32 = lane & 31;
    int head = l32 >> 3;
    unsigned wsh = (head & 1) << 4;        // 16-bit select shift, hoisted

    int beg = row_start[node];
    int end = row_start[node + 1];         // end-beg even, >= 2

    float l = 0.f;
    float acc[8] = {};

    uint4 r0 = rec[beg + half];
    uint4 r1 = rec[beg + 2 + half];
    uint4 r2 = rec[beg + 4 + half];
    uint4 r3 = rec[beg + 6 + half];

#define GATH(rr) (*(const uint4*)&hh[(size_t)(rr).x * 256 + l32 * 8])
#define PROC(rr, vv)                                                      \
    {                                                                     \
        unsigned u = (head & 2) ? (rr).z : (rr).y;                        \
        unsigned short us = (unsigned short)(u >> wsh);                   \
        float w = __half2float(*(const __half*)&us);                      \
        l += w;                                                           \
        const __half2* hp = (const __half2*)&(vv);                        \
        float2 f0 = __half22float2(hp[0]);                                \
        float2 f1 = __half22float2(hp[1]);                                \
        float2 f2 = __half22float2(hp[2]);                                \
        float2 f3 = __half22float2(hp[3]);                                \
        acc[0] = fmaf(w, f0.x, acc[0]); acc[1] = fmaf(w, f0.y, acc[1]);   \
        acc[2] = fmaf(w, f1.x, acc[2]); acc[3] = fmaf(w, f1.y, acc[3]);   \
        acc[4] = fmaf(w, f2.x, acc[4]); acc[5] = fmaf(w, f2.y, acc[5]);   \
        acc[6] = fmaf(w, f3.x, acc[6]); acc[7] = fmaf(w, f3.y, acc[7]);   \
    }

    uint4 h0 = GATH(r0);
    uint4 h1 = GATH(r1);
    uint4 h2 = GATH(r2);
    uint4 h3;

    int p = beg;
    while (p < end) {
        // phase 0 : pair at p
        h3 = GATH(r3);
        PROC(r0, h0);
        r0 = rec[p + 8 + half];
        p += 2;
        if (p >= end) break;
        // phase 1
        h0 = GATH(r0);
        PROC(r1, h1);
        r1 = rec[p + 8 + half];
        p += 2;
        if (p >= end) break;
        // phase 2
        h1 = GATH(r1);
        PROC(r2, h2);
        r2 = rec[p + 8 + half];
        p += 2;
        if (p >= end) break;
        // phase 3
        h2 = GATH(r2);
        PROC(r3, h3);
        r3 = rec[p + 8 + half];
        p += 2;
    }
#undef GATH
#undef PROC

    // combine the two halves (same node, disjoint edges, same channels)
    l += __shfl_xor(l, 32);
#pragma unroll
    for (int j = 0; j < 8; j++) acc[j] += __shfl_xor(acc[j], 32);

    if (half == 0) {
        float rcp = 1.f / l;
        float4 b0 = *(const float4*)&bias[l32 * 8];
        float4 b1 = *(const float4*)&bias[l32 * 8 + 4];
        float o[8];
        o[0] = fmaf(acc[0], rcp, b0.x); o[1] = fmaf(acc[1], rcp, b0.y);
        o[2] = fmaf(acc[2], rcp, b0.z); o[3] = fmaf(acc[3], rcp, b0.w);
        o[4] = fmaf(acc[4], rcp, b1.x); o[5] = fmaf(acc[5], rcp, b1.y);
        o[6] = fmaf(acc[6], rcp, b1.z); o[7] = fmaf(acc[7], rcp, b1.w);
#pragma unroll
        for (int j = 0; j < 8; j++)
            o[j] = (o[j] > 0.f) ? o[j] : __expf(o[j]) - 1.f;
        if constexpr (OUT_HALF) {
            __half2 q0 = __floats2half2_rn(o[0], o[1]);
            __half2 q1 = __floats2half2_rn(o[2], o[3]);
            __half2 q2 = __floats2half2_rn(o[4], o[5]);
            __half2 q3 = __floats2half2_rn(o[6], o[7]);
            uint4 pk = {*(unsigned*)&q0, *(unsigned*)&q1,
                        *(unsigned*)&q2, *(unsigned*)&q3};
            __half* outh = (__half*)outp;
            *(uint4*)&outh[(size_t)node * 256 + l32 * 8] = pk;
        } else {
            float* outf = (float*)outp;
            *(float4*)&outf[(size_t)node * 256 + l32 * 8] = *(float4*)&o[0];
            *(float4*)&outf[(size_t)node * 256 + l32 * 8 + 4] = *(float4*)&o[4];
        }
    }
}

// ---------------- launch ----------------

extern "C" void kernel_launch(void* const* d_in, const int* in_sizes, int n_in,
                              void* d_out, int out_size, void* d_ws, size_t ws_size,
                              hipStream_t stream) {
    const float* x   = (const float*)d_in[0];
    const int*   ei  = (const int*)d_in[1];
    const float* W1  = (const float*)d_in[2];
    const float* as1 = (const float*)d_in[3];
    const float* ad1 = (const float*)d_in[4];
    const float* b1  = (const float*)d_in[5];
    const float* W2  = (const float*)d_in[6];
    const float* as2 = (const float*)d_in[7];
    const float* ad2 = (const float*)d_in[8];
    const float* b2  = (const float*)d_in[9];
    float* out = (float*)d_out;

    const int N = in_sizes[0] / 128;
    const int E = in_sizes[1] / 2;
    const int Etot = E + N;
    const int EtotMax = Etot + N + 8;   // worst-case padded slots + pipeline pad
    const int NB = (N + 1023) / 1024;   // scan blocks (<= 64)

    // workspace layout (16B-aligned segments first)
    __half* h_half = (__half*)d_ws;                        // N*256 fp16
    __half* x1_h   = h_half + (size_t)N * 256;             // N*256 fp16 (x / x1)
    uint4*  rec    = (uint4*)(x1_h + (size_t)N * 256);     // EtotMax x 16B
    __half* a_s_h  = (__half*)(rec + EtotMax);             // N*4 fp16
    float*  a_d    = (float*)(a_s_h + (size_t)N * 4);      // N*4 fp32
    __half* Bt1    = (__half*)(a_d + (size_t)N * 4);       // 256*128 fp16
    __half* Bt2    = Bt1 + 256 * 128;                      // 256*256 fp16
    int*    cnt    = (int*)(Bt2 + 256 * 256);              // N
    int*    fill   = cnt + N;                              // N
    int*    row_st = fill + N;                             // N+2 (pad for align)
    int2*   edge_sd = (int2*)(row_st + (N + 2));           // EtotMax x 8B
    int*    partials = (int*)(edge_sd + EtotMax);          // NB+1

    hipMemsetAsync(cnt, 0, sizeof(int) * 2 * (size_t)N, stream);   // cnt + fill
    hipMemsetAsync(edge_sd, 0xFF, sizeof(int2) * (size_t)EtotMax, stream);

    const int xblocks = (N * 32 + 255) / 256;       // x->fp16 blocks
    const int eblocks = (Etot + 255) / 256;         // histogram / scatter blocks
    prep_kernel<<<384 + xblocks + eblocks, 256, 0, stream>>>(
        W1, Bt1, W2, Bt2, x, x1_h, ei, cnt, E, N, xblocks);

    scan_block<<<NB, 1024, 0, stream>>>(cnt, row_st, partials, N);
    scan_partials<<<1, 64, 0, stream>>>(partials, NB);
    scan_add<<<NB, 1024, 0, stream>>>(row_st, partials, N, NB);
    scatter_kernel<<<eblocks, 256, 0, stream>>>(ei, row_st, fill, edge_sd, E, Etot);

    dim3 ggrid(2 * ((N + 127) / 128));
    int ablocks = (N + 3) / 4;          // 4 nodes (waves) per 256-thread block
    int fblocks = (EtotMax + 255) / 256;

    // layer 1 (A = x pre-converted to fp16, living in the x1 buffer)
    gemm_mfma<128><<<ggrid, 256, 0, stream>>>(x1_h, Bt1, h_half,
                                              as1, ad1, a_s_h, a_d, N);
    fill_rec<<<fblocks, 256, 0, stream>>>(edge_sd, a_s_h, a_d, rec, EtotMax);
    gat_aggregate<true><<<ablocks, 256, 0, stream>>>(h_half, rec, row_st,
                                                     b1, x1_h, N);
    // layer 2
    gemm_mfma<256><<<ggrid, 256, 0, stream>>>(x1_h, Bt2, h_half,
                                              as2, ad2, a_s_h, a_d, N);
    fill_rec<<<fblocks, 256, 0, stream>>>(edge_sd, a_s_h, a_d, rec, EtotMax);
    gat_aggregate<false><<<ablocks, 256, 0, stream>>>(h_half, rec, row_st,
                                                      b2, out, N);
}

// Round 5
// 380.589 us; speedup vs baseline: 1.1051x; 1.0185x over previous
//
#include <hip/hip_runtime.h>
#include <hip/hip_fp16.h>
#include <math.h>

// ---------------------------------------------------------------------------
// GAT encoder, 2 layers.
//   GEMMs: single-term fp16 MFMA (mfma_f32_16x16x32_f16, fp32 accum),
//          register-prefetch double buffer (next K-step's global loads issued
//          under current step's MFMA). A fp16 (x up-front; x1 written fp16 by
//          aggregate-1); B pre-converted once to a transposed fp16 table.
//   Padded CSR: per-node degree rounded up to even; holes carry sentinel
//          records (src=0, w=0) so the aggregate inner loop has NO clamps
//          and NO tail checks.
//   fill_rec (2 edges/thread) computes w = exp(leaky(a_s[src]+a_d[dst]))
//          per edge per head; rec[i] = {src, w0|w1, w2|w3, 0} (fp16).
//   Aggregation: 1 node/wave, 2 edges/iteration (lanes 0-31 edge p, lanes
//          32-63 edge p+1; 16B/lane -> one 1KB gather per pair), depth-4
//          rotation-free software pipeline, prefetch distance 8 edges.
//          At the random-access HBM floor (~3.8 TB/s, FETCH compulsory).
// ---------------------------------------------------------------------------

#define LEAKY_SLOPE 0.2f

typedef __attribute__((ext_vector_type(8))) short short8v;      // 16B
typedef __attribute__((ext_vector_type(8))) _Float16 half8v;    // 8 fp16
typedef __attribute__((ext_vector_type(4))) float float4v;

// ---------------- fused prep: W->fp16 transposed + x->fp16 + histogram -----

__global__ void prep_kernel(const float* __restrict__ W1, __half* __restrict__ Bt1,
                            const float* __restrict__ W2, __half* __restrict__ Bt2,
                            const float* __restrict__ x, __half* __restrict__ x_h,
                            const int* __restrict__ ei, int* __restrict__ cnt,
                            int E, int N, int xblocks) {
    int b = blockIdx.x;
    if (b < 128) {                       // W1: [128][256] -> Bt1[c*128+k]
        int idx = b * 256 + threadIdx.x;
        int k = idx >> 8, c = idx & 255;
        Bt1[c * 128 + k] = __float2half(W1[idx]);
    } else if (b < 384) {                // W2: [256][256] -> Bt2[c*256+k]
        int idx = (b - 128) * 256 + threadIdx.x;
        int k = idx >> 8, c = idx & 255;
        Bt2[c * 256 + k] = __float2half(W2[idx]);
    } else if (b < 384 + xblocks) {      // x -> fp16, 4 elems/thread
        int t = (b - 384) * 256 + threadIdx.x;
        if (t < N * 32) {
            float4 v = *(const float4*)&x[(size_t)t * 4];
            __half2 h01 = __floats2half2_rn(v.x, v.y);
            __half2 h23 = __floats2half2_rn(v.z, v.w);
            uint2 pk = {*(unsigned*)&h01, *(unsigned*)&h23};
            *(uint2*)&x_h[(size_t)t * 4] = pk;
        }
    } else {                             // degree histogram (incl. self-loops)
        int e = (b - 384 - xblocks) * 256 + threadIdx.x;
        if (e < E + N) {
            int dst = (e < E) ? ei[E + e] : (e - E);
            atomicAdd(&cnt[dst], 1);
        }
    }
}

// ---------------- CSR build (padded to even degree) ----------------

__global__ __launch_bounds__(1024) void scan_block(const int* __restrict__ cnt,
                                                   int* __restrict__ row_start,
                                                   int* __restrict__ partials,
                                                   int n) {
    __shared__ int wsum[16];
    int tid = threadIdx.x, lane = tid & 63, wid = tid >> 6;
    int gi = blockIdx.x * 1024 + tid;
    int v = (gi < n) ? ((cnt[gi] + 1) & ~1) : 0;   // pad degree to even
    int x = v;
#pragma unroll
    for (int off = 1; off < 64; off <<= 1) {
        int y = __shfl_up(x, off, 64);
        if (lane >= off) x += y;
    }
    if (lane == 63) wsum[wid] = x;
    __syncthreads();
    if (wid == 0 && lane < 16) {
        int w = wsum[lane];
#pragma unroll
        for (int off = 1; off < 16; off <<= 1) {
            int y = __shfl_up(w, off, 16);
            if (lane >= off) w += y;
        }
        wsum[lane] = w;
    }
    __syncthreads();
    int excl = x - v + ((wid > 0) ? wsum[wid - 1] : 0);
    if (gi < n) row_start[gi] = excl;
    if (tid == 1023) partials[blockIdx.x] = wsum[15];
}

// scan_add with the partials-scan folded in (wave 0 redundantly scans <=64
// partials; saves the scan_partials launch).
__global__ __launch_bounds__(1024) void scan_add(int* __restrict__ row_start,
                                                 const int* __restrict__ partials,
                                                 int n, int nb) {
    __shared__ int spart[2];             // [excl prefix for this block, total]
    if (threadIdx.x < 64) {
        int lane = threadIdx.x;
        int v = (lane < nb) ? partials[lane] : 0;
        int x = v;
#pragma unroll
        for (int off = 1; off < 64; off <<= 1) {
            int y = __shfl_up(x, off, 64);
            if (lane >= off) x += y;
        }
        if (lane == (int)blockIdx.x) spart[0] = x - v;   // exclusive prefix
        if (lane == nb - 1) spart[1] = x;                // grand total
    }
    __syncthreads();
    int gi = blockIdx.x * 1024 + threadIdx.x;
    if (gi < n) row_start[gi] += spart[0];
    if (gi == 0) row_start[n] = spart[1];
}

__global__ void scatter_kernel(const int* __restrict__ ei,
                               const int* __restrict__ row_start,
                               int* __restrict__ fill,
                               int2* __restrict__ edge_sd, int E, int Etot) {
    int e = blockIdx.x * blockDim.x + threadIdx.x;
    if (e >= Etot) return;
    int src, dst;
    if (e < E) { src = ei[e]; dst = ei[E + e]; }
    else       { src = e - E; dst = e - E; }
    int pos = row_start[dst] + atomicAdd(&fill[dst], 1);
    edge_sd[pos] = make_int2(src, dst);
}

// rec[i] = {src, w0|w1, w2|w3, pad}, w = exp(leaky(a_s+a_d)) fp16.
// Sentinel slots (edge_sd memset 0xFF) -> zero record. 2 edges per thread.
__device__ __forceinline__ uint4 make_rec(int src, int dst,
                                          const __half* __restrict__ a_s_h,
                                          const float* __restrict__ a_d) {
    if (src < 0) {
        uint4 z = {0u, 0u, 0u, 0u};
        return z;
    }
    uint2 as2 = *(const uint2*)&a_s_h[(size_t)src * 4];
    float4 ad4 = *(const float4*)&a_d[(size_t)dst * 4];
    float2 f01 = __half22float2(*(const __half2*)&as2.x);
    float2 f23 = __half22float2(*(const __half2*)&as2.y);
    float e0 = f01.x + ad4.x, e1 = f01.y + ad4.y;
    float e2 = f23.x + ad4.z, e3 = f23.y + ad4.w;
    e0 = (e0 > 0.f) ? e0 : LEAKY_SLOPE * e0;
    e1 = (e1 > 0.f) ? e1 : LEAKY_SLOPE * e1;
    e2 = (e2 > 0.f) ? e2 : LEAKY_SLOPE * e2;
    e3 = (e3 > 0.f) ? e3 : LEAKY_SLOPE * e3;
    __half2 w01 = __floats2half2_rn(__expf(e0), __expf(e1));
    __half2 w23 = __floats2half2_rn(__expf(e2), __expf(e3));
    uint4 r = {(unsigned)src, *(unsigned*)&w01, *(unsigned*)&w23, 0u};
    return r;
}

__global__ void fill_rec(const int4* __restrict__ edge_sd2,
                         const __half* __restrict__ a_s_h,
                         const float* __restrict__ a_d,
                         uint4* __restrict__ rec, int npairs) {
    int i = blockIdx.x * blockDim.x + threadIdx.x;
    if (i >= npairs) return;
    int4 sd = edge_sd2[i];               // {src0,dst0,src1,dst1}
    uint4 r0 = make_rec(sd.x, sd.y, a_s_h, a_d);
    uint4 r1 = make_rec(sd.z, sd.w, a_s_h, a_d);
    rec[2 * i] = r0;
    rec[2 * i + 1] = r1;
}

// ---------------- fp16 MFMA GEMM + fused attention dots ---------------
// C[M,256] = A[M,K] @ B[K,256], C stored fp16. A fp16, B fp16 transposed.
// 128x128 tile, BK=32, 2x2 waves, 16 mfma per K-step, register prefetch.

template <int K>
__global__ __launch_bounds__(256) void gemm_mfma(
    const __half* __restrict__ Ah, const __half* __restrict__ Bt,
    __half* __restrict__ Ch,
    const float* __restrict__ att_src, const float* __restrict__ att_dst,
    __half* __restrict__ a_s_out, float* __restrict__ a_d_out, int M) {
    __shared__ short As[128][40];   // [m][k], pad 32->40
    __shared__ short Bs[128][40];   // [n][k] (transposed)

    const int col0 = (blockIdx.x & 1) * 128;
    const int row0 = (blockIdx.x >> 1) * 128;
    const int tid = threadIdx.x;
    const int lane = tid & 63;
    const int wave = tid >> 6;
    const int wr = wave >> 1, wc = wave & 1;
    const int quad = lane >> 4, lc = lane & 15;

    float4v acc[4][4] = {};

    const short* Abits = (const short*)Ah;
    const short* Bbits = (const short*)Bt;

    // staging geometry: thread covers rows (tid>>2) and (tid>>2)+64,
    // k-chunk (tid&3)*8, for both A and B.
    const int sr = tid >> 2;
    const int ko = (tid & 3) * 8;
    const int ga0 = row0 + sr, ga1 = ga0 + 64;
    const size_t gb0 = (size_t)(col0 + sr) * K + ko;
    const size_t gb1 = (size_t)(col0 + sr + 64) * K + ko;

    short8v pa0, pa1, pb0, pb1;
#define LOADT(k0)                                                          \
    {                                                                      \
        pa0 = {}; pa1 = {};                                                \
        if (ga0 < M) pa0 = *(const short8v*)&Abits[(size_t)ga0 * K + (k0) + ko]; \
        if (ga1 < M) pa1 = *(const short8v*)&Abits[(size_t)ga1 * K + (k0) + ko]; \
        pb0 = *(const short8v*)&Bbits[gb0 + (k0)];                         \
        pb1 = *(const short8v*)&Bbits[gb1 + (k0)];                         \
    }

    LOADT(0);

#pragma unroll
    for (int k0 = 0; k0 < K; k0 += 32) {
        *(short8v*)&As[sr][ko] = pa0;
        *(short8v*)&As[sr + 64][ko] = pa1;
        *(short8v*)&Bs[sr][ko] = pb0;
        *(short8v*)&Bs[sr + 64][ko] = pb1;
        __syncthreads();

        if (k0 + 32 < K) LOADT(k0 + 32);   // prefetch under MFMA

        half8v a[4], bv[4];
#pragma unroll
        for (int mt = 0; mt < 4; mt++) {
            int r = wr * 64 + mt * 16 + lc;
            a[mt] = *(const half8v*)&As[r][quad * 8];
        }
#pragma unroll
        for (int nt = 0; nt < 4; nt++) {
            int n = wc * 64 + nt * 16 + lc;
            bv[nt] = *(const half8v*)&Bs[n][quad * 8];
        }
#pragma unroll
        for (int mt = 0; mt < 4; mt++)
#pragma unroll
            for (int nt = 0; nt < 4; nt++)
                acc[mt][nt] = __builtin_amdgcn_mfma_f32_16x16x32_f16(
                    a[mt], bv[nt], acc[mt][nt], 0, 0, 0);
        __syncthreads();
    }
#undef LOADT

    // ---- epilogue: wave's 64 cols = head; C/D: col=lc(+nt*16), row=quad*4+r
    const int head = (col0 >> 6) + wc;
    float as_c[4], ad_c[4];
#pragma unroll
    for (int nt = 0; nt < 4; nt++) {
        as_c[nt] = att_src[head * 64 + nt * 16 + lc];
        ad_c[nt] = att_dst[head * 64 + nt * 16 + lc];
    }

#pragma unroll
    for (int mt = 0; mt < 4; mt++) {
#pragma unroll
        for (int r = 0; r < 4; r++) {
            int gr = row0 + wr * 64 + mt * 16 + quad * 4 + r;
            float ps = 0.f, pd = 0.f;
#pragma unroll
            for (int nt = 0; nt < 4; nt++) {
                float c = acc[mt][nt][r];
                ps = fmaf(c, as_c[nt], ps);
                pd = fmaf(c, ad_c[nt], pd);
                if (gr < M)
                    Ch[(size_t)gr * 256 + col0 + wc * 64 + nt * 16 + lc] =
                        __float2half(c);
            }
#pragma unroll
            for (int off = 1; off < 16; off <<= 1) {
                ps += __shfl_xor(ps, off, 64);
                pd += __shfl_xor(pd, off, 64);
            }
            if (lc == 0 && gr < M) {
                a_s_out[gr * 4 + head] = __float2half(ps);
                a_d_out[gr * 4 + head] = pd;
            }
        }
    }
}

// ---------------- fused aggregate + bias + elu ----------------
// 1 node/wave, 2 edges/iteration, padded-even rows: no clamps, no tail
// checks. Depth-4 rotation-free pipeline, prefetch distance 8 edges.
// At the random-access HBM floor (~3.8 TB/s effective).

template <bool OUT_HALF>
__global__ __launch_bounds__(256) void gat_aggregate(
    const __half* __restrict__ hh, const uint4* __restrict__ rec,
    const int* __restrict__ row_start, const float* __restrict__ bias,
    void* __restrict__ outp, int n) {
    int node = (blockIdx.x * blockDim.x + threadIdx.x) >> 6;
    if (node >= n) return;                 // wave-uniform
    int lane = threadIdx.x & 63;
    int half = lane >> 5, l32 = lane & 31;
    int head = l32 >> 3;
    unsigned wsh = (head & 1) << 4;        // 16-bit select shift, hoisted

    int beg = row_start[node];
    int end = row_start[node + 1];         // end-beg even, >= 2

    float l = 0.f;
    float acc[8] = {};

    uint4 r0 = rec[beg + half];
    uint4 r1 = rec[beg + 2 + half];
    uint4 r2 = rec[beg + 4 + half];
    uint4 r3 = rec[beg + 6 + half];

#define GATH(rr) (*(const uint4*)&hh[(size_t)(rr).x * 256 + l32 * 8])
#define PROC(rr, vv)                                                      \
    {                                                                     \
        unsigned u = (head & 2) ? (rr).z : (rr).y;                        \
        unsigned short us = (unsigned short)(u >> wsh);                   \
        float w = __half2float(*(const __half*)&us);                      \
        l += w;                                                           \
        const __half2* hp = (const __half2*)&(vv);                        \
        float2 f0 = __half22float2(hp[0]);                                \
        float2 f1 = __half22float2(hp[1]);                                \
        float2 f2 = __half22float2(hp[2]);                                \
        float2 f3 = __half22float2(hp[3]);                                \
        acc[0] = fmaf(w, f0.x, acc[0]); acc[1] = fmaf(w, f0.y, acc[1]);   \
        acc[2] = fmaf(w, f1.x, acc[2]); acc[3] = fmaf(w, f1.y, acc[3]);   \
        acc[4] = fmaf(w, f2.x, acc[4]); acc[5] = fmaf(w, f2.y, acc[5]);   \
        acc[6] = fmaf(w, f3.x, acc[6]); acc[7] = fmaf(w, f3.y, acc[7]);   \
    }

    uint4 h0 = GATH(r0);
    uint4 h1 = GATH(r1);
    uint4 h2 = GATH(r2);
    uint4 h3;

    int p = beg;
    while (p < end) {
        // phase 0 : pair at p
        h3 = GATH(r3);
        PROC(r0, h0);
        r0 = rec[p + 8 + half];
        p += 2;
        if (p >= end) break;
        // phase 1
        h0 = GATH(r0);
        PROC(r1, h1);
        r1 = rec[p + 8 + half];
        p += 2;
        if (p >= end) break;
        // phase 2
        h1 = GATH(r1);
        PROC(r2, h2);
        r2 = rec[p + 8 + half];
        p += 2;
        if (p >= end) break;
        // phase 3
        h2 = GATH(r2);
        PROC(r3, h3);
        r3 = rec[p + 8 + half];
        p += 2;
    }
#undef GATH
#undef PROC

    // combine the two halves (same node, disjoint edges, same channels)
    l += __shfl_xor(l, 32);
#pragma unroll
    for (int j = 0; j < 8; j++) acc[j] += __shfl_xor(acc[j], 32);

    if (half == 0) {
        float rcp = 1.f / l;
        float4 b0 = *(const float4*)&bias[l32 * 8];
        float4 b1 = *(const float4*)&bias[l32 * 8 + 4];
        float o[8];
        o[0] = fmaf(acc[0], rcp, b0.x); o[1] = fmaf(acc[1], rcp, b0.y);
        o[2] = fmaf(acc[2], rcp, b0.z); o[3] = fmaf(acc[3], rcp, b0.w);
        o[4] = fmaf(acc[4], rcp, b1.x); o[5] = fmaf(acc[5], rcp, b1.y);
        o[6] = fmaf(acc[6], rcp, b1.z); o[7] = fmaf(acc[7], rcp, b1.w);
#pragma unroll
        for (int j = 0; j < 8; j++)
            o[j] = (o[j] > 0.f) ? o[j] : __expf(o[j]) - 1.f;
        if constexpr (OUT_HALF) {
            __half2 q0 = __floats2half2_rn(o[0], o[1]);
            __half2 q1 = __floats2half2_rn(o[2], o[3]);
            __half2 q2 = __floats2half2_rn(o[4], o[5]);
            __half2 q3 = __floats2half2_rn(o[6], o[7]);
            uint4 pk = {*(unsigned*)&q0, *(unsigned*)&q1,
                        *(unsigned*)&q2, *(unsigned*)&q3};
            __half* outh = (__half*)outp;
            *(uint4*)&outh[(size_t)node * 256 + l32 * 8] = pk;
        } else {
            float* outf = (float*)outp;
            *(float4*)&outf[(size_t)node * 256 + l32 * 8] = *(float4*)&o[0];
            *(float4*)&outf[(size_t)node * 256 + l32 * 8 + 4] = *(float4*)&o[4];
        }
    }
}

// ---------------- launch ----------------

extern "C" void kernel_launch(void* const* d_in, const int* in_sizes, int n_in,
                              void* d_out, int out_size, void* d_ws, size_t ws_size,
                              hipStream_t stream) {
    const float* x   = (const float*)d_in[0];
    const int*   ei  = (const int*)d_in[1];
    const float* W1  = (const float*)d_in[2];
    const float* as1 = (const float*)d_in[3];
    const float* ad1 = (const float*)d_in[4];
    const float* b1  = (const float*)d_in[5];
    const float* W2  = (const float*)d_in[6];
    const float* as2 = (const float*)d_in[7];
    const float* ad2 = (const float*)d_in[8];
    const float* b2  = (const float*)d_in[9];
    float* out = (float*)d_out;

    const int N = in_sizes[0] / 128;
    const int E = in_sizes[1] / 2;
    const int Etot = E + N;
    const int EtotMax = (Etot + N + 9) & ~1;  // padded slots + pipeline pad, even
    const int NB = (N + 1023) / 1024;         // scan blocks (<= 64)

    // workspace layout (16B-aligned segments first)
    __half* h_half = (__half*)d_ws;                        // N*256 fp16
    __half* x1_h   = h_half + (size_t)N * 256;             // N*256 fp16 (x / x1)
    uint4*  rec    = (uint4*)(x1_h + (size_t)N * 256);     // EtotMax x 16B
    __half* a_s_h  = (__half*)(rec + EtotMax);             // N*4 fp16
    float*  a_d    = (float*)(a_s_h + (size_t)N * 4);      // N*4 fp32
    __half* Bt1    = (__half*)(a_d + (size_t)N * 4);       // 256*128 fp16
    __half* Bt2    = Bt1 + 256 * 128;                      // 256*256 fp16
    int*    cnt    = (int*)(Bt2 + 256 * 256);              // N
    int*    fill   = cnt + N;                              // N
    int*    row_st = fill + N;                             // N+2 (pad for align)
    int2*   edge_sd = (int2*)(row_st + (N + 2));           // EtotMax x 8B
    int*    partials = (int*)(edge_sd + EtotMax);          // NB+1

    hipMemsetAsync(cnt, 0, sizeof(int) * 2 * (size_t)N, stream);   // cnt + fill
    hipMemsetAsync(edge_sd, 0xFF, sizeof(int2) * (size_t)EtotMax, stream);

    const int xblocks = (N * 32 + 255) / 256;       // x->fp16 blocks
    const int eblocks = (Etot + 255) / 256;         // histogram / scatter blocks
    prep_kernel<<<384 + xblocks + eblocks, 256, 0, stream>>>(
        W1, Bt1, W2, Bt2, x, x1_h, ei, cnt, E, N, xblocks);

    scan_block<<<NB, 1024, 0, stream>>>(cnt, row_st, partials, N);
    scan_add<<<NB, 1024, 0, stream>>>(row_st, partials, N, NB);
    scatter_kernel<<<eblocks, 256, 0, stream>>>(ei, row_st, fill, edge_sd, E, Etot);

    dim3 ggrid(2 * ((N + 127) / 128));
    int ablocks = (N + 3) / 4;          // 4 nodes (waves) per 256-thread block
    int npairs = EtotMax / 2;
    int fblocks = (npairs + 255) / 256;

    // layer 1 (A = x pre-converted to fp16, living in the x1 buffer)
    gemm_mfma<128><<<ggrid, 256, 0, stream>>>(x1_h, Bt1, h_half,
                                              as1, ad1, a_s_h, a_d, N);
    fill_rec<<<fblocks, 256, 0, stream>>>((const int4*)edge_sd, a_s_h, a_d,
                                          rec, npairs);
    gat_aggregate<true><<<ablocks, 256, 0, stream>>>(h_half, rec, row_st,
                                                     b1, x1_h, N);
    // layer 2
    gemm_mfma<256><<<ggrid, 256, 0, stream>>>(x1_h, Bt2, h_half,
                                              as2, ad2, a_s_h, a_d, N);
    fill_rec<<<fblocks, 256, 0, stream>>>((const int4*)edge_sd, a_s_h, a_d,
                                          rec, npairs);
    gat_aggregate<false><<<ablocks, 256, 0, stream>>>(h_half, rec, row_st,
                                                      b2, out, N);
}